// Round 2
// 1137.041 us; speedup vs baseline: 1.2822x; 1.2822x over previous
//
#include <hip/hip_runtime.h>
#include <hip/hip_bf16.h>
#include <math.h>

#define B_    4
#define H_    64
#define W_    128
#define WF_   65
#define D_    768
#define NB_   8
#define BS_   96
#define HID_  3072
#define NTOK_ 32768
#define CHTOK_ 8192
#define LAM_  0.01f

typedef __hip_bfloat16 bf16;
typedef __attribute__((ext_vector_type(8))) short bf16x8;
typedef __attribute__((ext_vector_type(4))) float f32x4;
typedef unsigned int u32;

__device__ __forceinline__ float ldf(const float* p) { return *p; }
__device__ __forceinline__ float ldf(const bf16* p)  { return __bfloat162float(*p); }
__device__ __forceinline__ void stf(float* p, float v) { *p = v; }
__device__ __forceinline__ void stf(bf16* p, float v)  { *p = __float2bfloat16(v); }

#define GLOAD_LDS16(g, l) \
  __builtin_amdgcn_global_load_lds((const __attribute__((address_space(1))) u32*)(g), \
                                   (__attribute__((address_space(3))) u32*)(l), 16, 0, 0)

// fragment read from LDS row-major [row][Kpad]
#define FRAG(arr, KP, row, kof) (*(const bf16x8*)((arr) + (size_t)(row) * (KP) + (kof)))

// ---------------- LayerNorm (one block per token, 768 = 3*256) ----------------
template <typename TIN>
__global__ __launch_bounds__(256) void ln_kernel(
    const TIN* __restrict__ x, const float* __restrict__ g,
    const float* __restrict__ bta, bf16* __restrict__ out) {
  __shared__ float sred[8];
  const size_t base = (size_t)blockIdx.x * D_;
  const int t = threadIdx.x;
  float v0 = ldf(x + base + t);
  float v1 = ldf(x + base + t + 256);
  float v2 = ldf(x + base + t + 512);
  float s = v0 + v1 + v2;
  #pragma unroll
  for (int o = 32; o; o >>= 1) s += __shfl_down(s, o, 64);
  int lane = t & 63, wid = t >> 6;
  if (lane == 0) sred[wid] = s;
  __syncthreads();
  if (t == 0) sred[0] = sred[0] + sred[1] + sred[2] + sred[3];
  __syncthreads();
  float mean = sred[0] * (1.0f / D_);
  float d0 = v0 - mean, d1 = v1 - mean, d2 = v2 - mean;
  float q = d0 * d0 + d1 * d1 + d2 * d2;
  #pragma unroll
  for (int o = 32; o; o >>= 1) q += __shfl_down(q, o, 64);
  if (lane == 0) sred[4 + wid] = q;
  __syncthreads();
  if (t == 0) sred[4] = sred[4] + sred[5] + sred[6] + sred[7];
  __syncthreads();
  float rstd = rsqrtf(sred[4] * (1.0f / D_) + 1e-5f);
  stf(out + base + t,       d0 * rstd * g[t]       + bta[t]);
  stf(out + base + t + 256, d1 * rstd * g[t + 256] + bta[t + 256]);
  stf(out + base + t + 512, d2 * rstd * g[t + 512] + bta[t + 512]);
}

// ============ S1: rfft along W as MFMA GEMM. block=(bh, ctile64) ============
// Fr/Fi[(bh,f), c] = sum_w C1/C2[f,w] * xn[(bh,w), c]
__global__ __launch_bounds__(256) void s1_rfftw(
    const bf16* __restrict__ xn, bf16* __restrict__ fr, bf16* __restrict__ fi) {
  const int KP = 136;  // 128 + pad (272 B rows, 16B aligned)
  __shared__ __align__(16) bf16 sC1[80 * 136];
  __shared__ __align__(16) bf16 sC2[80 * 136];
  __shared__ __align__(16) bf16 sXt[64 * 136];
  const int t = threadIdx.x;
  const int bh = blockIdx.x;
  const int c0 = blockIdx.y * 64;
  const float s1 = 0.011048543456039806f;  // 1/sqrt(8192)

  // LUT gen: rows f=0..79 (65..79 finite garbage, stores skipped)
  for (int e = t; e < 80 * 128; e += 256) {
    int f = e >> 7, w = e & 127;
    int p = (f * w) & 127;
    float a = p * 0.04908738521234052f;  // 2*pi/128
    sC1[f * KP + w] = __float2bfloat16(s1 * cosf(a));
    sC2[f * KP + w] = __float2bfloat16(-s1 * sinf(a));
  }
  // stage xn tile transposed: sXt[c][w]
  {
    const int cv = (t & 7) * 8;
    #pragma unroll
    for (int rep = 0; rep < 4; ++rep) {
      int w = (t >> 3) + 32 * rep;
      bf16x8 v = *(const bf16x8*)(xn + ((size_t)bh * W_ + w) * D_ + c0 + cv);
      #pragma unroll
      for (int i = 0; i < 8; ++i) sXt[(cv + i) * KP + w] = ((const bf16*)&v)[i];
    }
  }
  __syncthreads();

  const int wave = t >> 6, lane = t & 63, l16 = lane & 15, quad = lane >> 4;
  const int ni = (wave == 0) ? 2 : 1;
  int itile[2] = {wave, 4};
  f32x4 accR[2][4], accI[2][4];
  #pragma unroll
  for (int ii = 0; ii < 2; ++ii)
    #pragma unroll
    for (int j = 0; j < 4; ++j) { accR[ii][j] = (f32x4){0,0,0,0}; accI[ii][j] = (f32x4){0,0,0,0}; }

  for (int s = 0; s < 4; ++s) {
    const int kof = s * 32 + quad * 8;
    bf16x8 bfrag[4];
    #pragma unroll
    for (int j = 0; j < 4; ++j) bfrag[j] = FRAG(sXt, KP, j * 16 + l16, kof);
    for (int ii = 0; ii < ni; ++ii) {
      const int arow = 16 * itile[ii] + l16;
      bf16x8 a1 = FRAG(sC1, KP, arow, kof);
      bf16x8 a2 = FRAG(sC2, KP, arow, kof);
      #pragma unroll
      for (int j = 0; j < 4; ++j) {
        accR[ii][j] = __builtin_amdgcn_mfma_f32_16x16x32_bf16(a1, bfrag[j], accR[ii][j], 0, 0, 0);
        accI[ii][j] = __builtin_amdgcn_mfma_f32_16x16x32_bf16(a2, bfrag[j], accI[ii][j], 0, 0, 0);
      }
    }
  }
  for (int ii = 0; ii < ni; ++ii) {
    #pragma unroll
    for (int r = 0; r < 4; ++r) {
      const int f = 16 * itile[ii] + quad * 4 + r;
      if (f >= WF_) continue;
      const size_t ob = ((size_t)bh * WF_ + f) * D_ + c0;
      #pragma unroll
      for (int j = 0; j < 4; ++j) {
        fr[ob + j * 16 + l16] = __float2bfloat16(accR[ii][j][r]);
        fi[ob + j * 16 + l16] = __float2bfloat16(accI[ii][j][r]);
      }
    }
  }
}

// ============ S2: FFT along H as MFMA GEMM. block=(b*WF+f, ctile64) ============
// G[k,c] = sum_h T[k,h] * F[h,c],  T = exp(esign * i 2pi k h / 64)
__global__ __launch_bounds__(256) void s2_ffth(
    const bf16* __restrict__ inr, const bf16* __restrict__ ini,
    bf16* __restrict__ outr, bf16* __restrict__ outi, float esign) {
  const int KP = 72;  // 64 + pad (144 B rows)
  __shared__ __align__(16) bf16 sTr[64 * 72];
  __shared__ __align__(16) bf16 sTi[64 * 72];
  __shared__ __align__(16) bf16 sTn[64 * 72];
  __shared__ __align__(16) bf16 sFtr[64 * 72];
  __shared__ __align__(16) bf16 sFti[64 * 72];
  const int t = threadIdx.x;
  const int b = blockIdx.x / WF_;
  const int f = blockIdx.x % WF_;
  const int c0 = blockIdx.y * 64;

  for (int e = t; e < 64 * 64; e += 256) {
    int k = e >> 6, h = e & 63;
    int p = (k * h) & 63;
    float a = p * 0.09817477042468103f;  // 2*pi/64
    float c = cosf(a), s = esign * sinf(a);
    sTr[k * KP + h] = __float2bfloat16(c);
    sTi[k * KP + h] = __float2bfloat16(s);
    sTn[k * KP + h] = __float2bfloat16(-s);
  }
  {
    const int cv = (t & 7) * 8;
    #pragma unroll
    for (int rep = 0; rep < 2; ++rep) {
      int h = (t >> 3) + 32 * rep;
      size_t g = ((size_t)(b * H_ + h) * WF_ + f) * D_ + c0 + cv;
      bf16x8 vr = *(const bf16x8*)(inr + g);
      bf16x8 vi = *(const bf16x8*)(ini + g);
      #pragma unroll
      for (int i = 0; i < 8; ++i) {
        sFtr[(cv + i) * KP + h] = ((const bf16*)&vr)[i];
        sFti[(cv + i) * KP + h] = ((const bf16*)&vi)[i];
      }
    }
  }
  __syncthreads();

  const int wave = t >> 6, lane = t & 63, l16 = lane & 15, quad = lane >> 4;
  f32x4 accR[4], accI[4];
  #pragma unroll
  for (int j = 0; j < 4; ++j) { accR[j] = (f32x4){0,0,0,0}; accI[j] = (f32x4){0,0,0,0}; }

  #pragma unroll
  for (int s = 0; s < 2; ++s) {
    const int kof = s * 32 + quad * 8;
    const int arow = 16 * wave + l16;
    bf16x8 ar = FRAG(sTr, KP, arow, kof);
    bf16x8 ai = FRAG(sTi, KP, arow, kof);
    bf16x8 an = FRAG(sTn, KP, arow, kof);
    #pragma unroll
    for (int j = 0; j < 4; ++j) {
      const int brow = j * 16 + l16;
      bf16x8 br = FRAG(sFtr, KP, brow, kof);
      bf16x8 bi = FRAG(sFti, KP, brow, kof);
      accR[j] = __builtin_amdgcn_mfma_f32_16x16x32_bf16(ar, br, accR[j], 0, 0, 0);
      accR[j] = __builtin_amdgcn_mfma_f32_16x16x32_bf16(an, bi, accR[j], 0, 0, 0);
      accI[j] = __builtin_amdgcn_mfma_f32_16x16x32_bf16(ai, br, accI[j], 0, 0, 0);
      accI[j] = __builtin_amdgcn_mfma_f32_16x16x32_bf16(ar, bi, accI[j], 0, 0, 0);
    }
  }
  #pragma unroll
  for (int r = 0; r < 4; ++r) {
    const int k = 16 * wave + quad * 4 + r;
    const size_t ob = ((size_t)(b * H_ + k) * WF_ + f) * D_ + c0;
    #pragma unroll
    for (int j = 0; j < 4; ++j) {
      outr[ob + j * 16 + l16] = __float2bfloat16(accR[j][r]);
      outi[ob + j * 16 + l16] = __float2bfloat16(accI[j][r]);
    }
  }
}

// ============ S3: irfft along W + residual, MFMA. block=(bh, ctile64) ============
// x[w,c] = sum_f Cr[w,f]*Fr[f,c] + Ci[w,f]*Fi[f,c];  K padded 65->96 (zero rows)
__global__ __launch_bounds__(256) void s3_irfftw(
    const bf16* __restrict__ fr, const bf16* __restrict__ fi,
    const float* __restrict__ x0, bf16* __restrict__ xsp) {
  const int KP = 104;  // 96 + pad (208 B rows)
  __shared__ __align__(16) bf16 sCr[128 * 104];
  __shared__ __align__(16) bf16 sCi[128 * 104];
  __shared__ __align__(16) bf16 sGtr[64 * 104];
  __shared__ __align__(16) bf16 sGti[64 * 104];
  const int t = threadIdx.x;
  const int bh = blockIdx.x;
  const int c0 = blockIdx.y * 64;
  const float s1 = 0.011048543456039806f;

  for (int e = t; e < 128 * 96; e += 256) {
    int w = e / 96, f = e - w * 96;
    float cr = 0.f, ci = 0.f;
    if (f < WF_) {
      int p = (f * w) & 127;
      float a = p * 0.04908738521234052f;
      float al = (f == 0 || f == 64) ? 1.0f : 2.0f;
      cr = s1 * al * cosf(a);
      ci = -s1 * al * sinf(a);
    }
    sCr[w * KP + f] = __float2bfloat16(cr);
    sCi[w * KP + f] = __float2bfloat16(ci);
  }
  {
    const int cv = (t & 7) * 8;
    #pragma unroll
    for (int rep = 0; rep < 2; ++rep) {
      int f = (t >> 3) + 32 * rep;
      size_t g = ((size_t)bh * WF_ + f) * D_ + c0 + cv;
      bf16x8 vr = *(const bf16x8*)(fr + g);
      bf16x8 vi = *(const bf16x8*)(fi + g);
      #pragma unroll
      for (int i = 0; i < 8; ++i) {
        sGtr[(cv + i) * KP + f] = ((const bf16*)&vr)[i];
        sGti[(cv + i) * KP + f] = ((const bf16*)&vi)[i];
      }
    }
    if (t < 8) {  // f = 64 row
      size_t g = ((size_t)bh * WF_ + 64) * D_ + c0 + cv;
      bf16x8 vr = *(const bf16x8*)(fr + g);
      bf16x8 vi = *(const bf16x8*)(fi + g);
      #pragma unroll
      for (int i = 0; i < 8; ++i) {
        sGtr[(cv + i) * KP + 64] = ((const bf16*)&vr)[i];
        sGti[(cv + i) * KP + 64] = ((const bf16*)&vi)[i];
      }
    }
    // zero pad rows f=65..95 (avoid NaN from poisoned LDS)
    const bf16 z = __float2bfloat16(0.f);
    for (int e = t; e < 64 * 31; e += 256) {
      int c = e / 31, f = 65 + (e - (e / 31) * 31);
      sGtr[c * KP + f] = z;
      sGti[c * KP + f] = z;
    }
  }
  __syncthreads();

  const int wave = t >> 6, lane = t & 63, l16 = lane & 15, quad = lane >> 4;
  f32x4 acc[2][4];
  #pragma unroll
  for (int ii = 0; ii < 2; ++ii)
    #pragma unroll
    for (int j = 0; j < 4; ++j) acc[ii][j] = (f32x4){0,0,0,0};

  #pragma unroll
  for (int s = 0; s < 3; ++s) {
    const int kof = s * 32 + quad * 8;
    bf16x8 br[4], bi[4];
    #pragma unroll
    for (int j = 0; j < 4; ++j) {
      br[j] = FRAG(sGtr, KP, j * 16 + l16, kof);
      bi[j] = FRAG(sGti, KP, j * 16 + l16, kof);
    }
    #pragma unroll
    for (int ii = 0; ii < 2; ++ii) {
      const int arow = 16 * (wave + 4 * ii) + l16;
      bf16x8 a1 = FRAG(sCr, KP, arow, kof);
      bf16x8 a2 = FRAG(sCi, KP, arow, kof);
      #pragma unroll
      for (int j = 0; j < 4; ++j) {
        acc[ii][j] = __builtin_amdgcn_mfma_f32_16x16x32_bf16(a1, br[j], acc[ii][j], 0, 0, 0);
        acc[ii][j] = __builtin_amdgcn_mfma_f32_16x16x32_bf16(a2, bi[j], acc[ii][j], 0, 0, 0);
      }
    }
  }
  #pragma unroll
  for (int ii = 0; ii < 2; ++ii) {
    #pragma unroll
    for (int r = 0; r < 4; ++r) {
      const int w = 16 * (wave + 4 * ii) + quad * 4 + r;
      const size_t ob = ((size_t)bh * W_ + w) * D_ + c0;
      #pragma unroll
      for (int j = 0; j < 4; ++j) {
        const size_t o = ob + j * 16 + l16;
        xsp[o] = __float2bfloat16(acc[ii][j][r] + x0[o]);
      }
    }
  }
}

// ============ block-diagonal complex MLP as MFMA, in place ============
// grid = (nspec/64, NB_), block = 256 (4 waves).
// Per block: 64 positions x one 96-wide channel block.
// sA rows 0..63  = u = xr - xi   (layer1 A), later p = o1r - o1i (layer2 A)
// sA rows 64..127= v = xr + xi,  later q = o1r + o1i
// sW[m][j] = W[j][m] (transposed weight), staged W1 then re-staged W2.
__global__ __launch_bounds__(256) void blockmlp_mfma(
    bf16* __restrict__ gr, bf16* __restrict__ gi,
    const float* __restrict__ w1, const float* __restrict__ b1,
    const float* __restrict__ w2, const float* __restrict__ b2) {
  const int KP = 104;  // 96 + pad (208 B rows: 13x16B slots -> conflict-free b128)
  __shared__ __align__(16) bf16 sA[128 * 104];
  __shared__ __align__(16) bf16 sW[96 * 104];
  const int t = threadIdx.x;
  const int p0 = blockIdx.x * 64;
  const int nb = blockIdx.y;
  const int cbase = nb * BS_;

  // ---- stage u,v (64 rows x 12 bf16x8 vectors each) ----
  #pragma unroll
  for (int it = 0; it < 3; ++it) {
    int task = t + 256 * it;          // 0..767
    int r = task / 12, jv = task - r * 12;
    size_t g = (size_t)(p0 + r) * D_ + cbase + jv * 8;
    bf16x8 vr = *(const bf16x8*)(gr + g);
    bf16x8 vi = *(const bf16x8*)(gi + g);
    bf16x8 u8, v8;
    #pragma unroll
    for (int i = 0; i < 8; ++i) {
      float xr = __bfloat162float(((const bf16*)&vr)[i]);
      float xi = __bfloat162float(((const bf16*)&vi)[i]);
      ((bf16*)&u8)[i] = __float2bfloat16(xr - xi);
      ((bf16*)&v8)[i] = __float2bfloat16(xr + xi);
    }
    *(bf16x8*)(sA + r * KP + jv * 8) = u8;
    *(bf16x8*)(sA + (64 + r) * KP + jv * 8) = v8;
  }
  // ---- stage W1^T: sW[m][j] = w1[nb][j][m] ----
  {
    const float* wsrc = w1 + nb * BS_ * BS_;
    #pragma unroll
    for (int it = 0; it < 9; ++it) {
      int e4 = t + 256 * it;          // 0..2303 tasks of 4 elems
      int j = e4 / 24, m4 = (e4 - j * 24) * 4;
      float4 ld = *(const float4*)(wsrc + j * 96 + m4);
      sW[(m4 + 0) * KP + j] = __float2bfloat16(ld.x);
      sW[(m4 + 1) * KP + j] = __float2bfloat16(ld.y);
      sW[(m4 + 2) * KP + j] = __float2bfloat16(ld.z);
      sW[(m4 + 3) * KP + j] = __float2bfloat16(ld.w);
    }
  }
  __syncthreads();

  const int wave = t >> 6, lane = t & 63, l16 = lane & 15, quad = lane >> 4;
  // wave owns u rows [wave*16, wave*16+16) and matching v rows (+64)
  f32x4 accU[6], accV[6];
  #pragma unroll
  for (int n = 0; n < 6; ++n) { accU[n] = (f32x4){0,0,0,0}; accV[n] = (f32x4){0,0,0,0}; }

  #pragma unroll
  for (int s = 0; s < 3; ++s) {
    const int kof = s * 32 + quad * 8;
    bf16x8 au = FRAG(sA, KP, wave * 16 + l16, kof);
    bf16x8 av = FRAG(sA, KP, 64 + wave * 16 + l16, kof);
    bf16x8 bw[6];
    #pragma unroll
    for (int n = 0; n < 6; ++n) bw[n] = FRAG(sW, KP, n * 16 + l16, kof);
    #pragma unroll
    for (int n = 0; n < 6; ++n) {
      accU[n] = __builtin_amdgcn_mfma_f32_16x16x32_bf16(au, bw[n], accU[n], 0, 0, 0);
      accV[n] = __builtin_amdgcn_mfma_f32_16x16x32_bf16(av, bw[n], accV[n], 0, 0, 0);
    }
  }
  __syncthreads();  // all layer-1 reads of sA/sW complete

  // ---- re-stage W2^T (overwrites sW) ----
  {
    const float* wsrc = w2 + nb * BS_ * BS_;
    #pragma unroll
    for (int it = 0; it < 9; ++it) {
      int e4 = t + 256 * it;
      int j = e4 / 24, m4 = (e4 - j * 24) * 4;
      float4 ld = *(const float4*)(wsrc + j * 96 + m4);
      sW[(m4 + 0) * KP + j] = __float2bfloat16(ld.x);
      sW[(m4 + 1) * KP + j] = __float2bfloat16(ld.y);
      sW[(m4 + 2) * KP + j] = __float2bfloat16(ld.z);
      sW[(m4 + 3) * KP + j] = __float2bfloat16(ld.w);
    }
  }
  // ---- relu + combine into p,q; write back into sA ----
  #pragma unroll
  for (int n = 0; n < 6; ++n) {
    const float bias = b1[cbase + n * 16 + l16];
    #pragma unroll
    for (int r = 0; r < 4; ++r) {
      float o1r = fmaxf(accU[n][r] + bias, 0.0f);
      float o1i = fmaxf(accV[n][r] + bias, 0.0f);
      const int row = wave * 16 + quad * 4 + r;
      sA[row * KP + n * 16 + l16]        = __float2bfloat16(o1r - o1i);  // p
      sA[(64 + row) * KP + n * 16 + l16] = __float2bfloat16(o1r + o1i);  // q
    }
  }
  __syncthreads();

  // ---- layer 2: accP = p @ W2, accQ = q @ W2 ----
  #pragma unroll
  for (int n = 0; n < 6; ++n) { accU[n] = (f32x4){0,0,0,0}; accV[n] = (f32x4){0,0,0,0}; }
  #pragma unroll
  for (int s = 0; s < 3; ++s) {
    const int kof = s * 32 + quad * 8;
    bf16x8 ap = FRAG(sA, KP, wave * 16 + l16, kof);
    bf16x8 aq = FRAG(sA, KP, 64 + wave * 16 + l16, kof);
    bf16x8 bw[6];
    #pragma unroll
    for (int n = 0; n < 6; ++n) bw[n] = FRAG(sW, KP, n * 16 + l16, kof);
    #pragma unroll
    for (int n = 0; n < 6; ++n) {
      accU[n] = __builtin_amdgcn_mfma_f32_16x16x32_bf16(ap, bw[n], accU[n], 0, 0, 0);
      accV[n] = __builtin_amdgcn_mfma_f32_16x16x32_bf16(aq, bw[n], accV[n], 0, 0, 0);
    }
  }

  // ---- bias + softshrink + store ----
  #pragma unroll
  for (int n = 0; n < 6; ++n) {
    const float bias = b2[cbase + n * 16 + l16];
    #pragma unroll
    for (int r = 0; r < 4; ++r) {
      const int row = wave * 16 + quad * 4 + r;
      float o2r = accU[n][r] + bias;
      float o2i = accV[n][r] + bias;
      o2r = (o2r > LAM_) ? (o2r - LAM_) : ((o2r < -LAM_) ? (o2r + LAM_) : 0.0f);
      o2i = (o2i > LAM_) ? (o2i - LAM_) : ((o2i < -LAM_) ? (o2i + LAM_) : 0.0f);
      const size_t o = (size_t)(p0 + row) * D_ + cbase + n * 16 + l16;
      gr[o] = __float2bfloat16(o2r);
      gi[o] = __float2bfloat16(o2i);
    }
  }
}

// ---------------- weight transpose+cast: W (K x N fp32) -> Wt (N x K bf16) ----
__global__ __launch_bounds__(256) void wtrans_kernel(
    const float* __restrict__ Wm, bf16* __restrict__ Wt, int K, int N) {
  __shared__ float tile[32][33];
  const int n0 = blockIdx.x * 32;
  const int k0 = blockIdx.y * 32;
  const int tx = threadIdx.x & 31;
  const int ty = threadIdx.x >> 5;   // 0..7
  #pragma unroll
  for (int r = 0; r < 32; r += 8)
    tile[ty + r][tx] = Wm[(size_t)(k0 + ty + r) * N + n0 + tx];
  __syncthreads();
  #pragma unroll
  for (int r = 0; r < 32; r += 8)
    Wt[(size_t)(n0 + ty + r) * K + k0 + tx] = __float2bfloat16(tile[tx][ty + r]);
}

// ---------------- MFMA GEMM: out = act(A @ Bt^T + bias) [+ resid] ----------------
template <int MODE, typename TOUT>
__global__ __launch_bounds__(256) void mfma_gemm_kernel(
    const bf16* __restrict__ A, const bf16* __restrict__ Bt,
    const float* __restrict__ bias, const bf16* __restrict__ resid,
    TOUT* __restrict__ out, int M, int N, int K) {
  __shared__ __align__(16) bf16 As[128 * 32];
  __shared__ __align__(16) bf16 Bs[128 * 32];
  const int t = threadIdx.x;
  const int m0 = blockIdx.x * 128;
  const int n0 = blockIdx.y * 128;
  const int wave = t >> 6;
  const int lane = t & 63;
  const int wm = (wave & 1) * 64;
  const int wn = (wave >> 1) * 64;
  const int l16 = lane & 15;
  const int quad = lane >> 4;

  const int srow = t >> 2;
  const int skof = (t & 3) * 8;
  const bf16* Ag0 = A + (size_t)(m0 + srow) * K + skof;
  const bf16* Ag1 = A + (size_t)(m0 + 64 + srow) * K + skof;
  const bf16* Bg0 = Bt + (size_t)(n0 + srow) * K + skof;
  const bf16* Bg1 = Bt + (size_t)(n0 + 64 + srow) * K + skof;
  bf16* Al0 = As + t * 8;
  bf16* Al1 = As + 2048 + t * 8;
  bf16* Bl0 = Bs + t * 8;
  bf16* Bl1 = Bs + 2048 + t * 8;

  f32x4 acc[4][4];
  #pragma unroll
  for (int i = 0; i < 4; ++i)
    #pragma unroll
    for (int j = 0; j < 4; ++j) acc[i][j] = (f32x4){0.f, 0.f, 0.f, 0.f};

  for (int k0 = 0; k0 < K; k0 += 32) {
    __syncthreads();
    GLOAD_LDS16(Ag0 + k0, Al0);
    GLOAD_LDS16(Ag1 + k0, Al1);
    GLOAD_LDS16(Bg0 + k0, Bl0);
    GLOAD_LDS16(Bg1 + k0, Bl1);
    __syncthreads();
    bf16x8 af[4], bfr[4];
    #pragma unroll
    for (int i = 0; i < 4; ++i)
      af[i] = *(const bf16x8*)(As + (wm + i * 16 + l16) * 32 + quad * 8);
    #pragma unroll
    for (int j = 0; j < 4; ++j)
      bfr[j] = *(const bf16x8*)(Bs + (wn + j * 16 + l16) * 32 + quad * 8);
    #pragma unroll
    for (int i = 0; i < 4; ++i)
      #pragma unroll
      for (int j = 0; j < 4; ++j)
        acc[i][j] = __builtin_amdgcn_mfma_f32_16x16x32_bf16(af[i], bfr[j], acc[i][j], 0, 0, 0);
  }

  #pragma unroll
  for (int i = 0; i < 4; ++i) {
    #pragma unroll
    for (int j = 0; j < 4; ++j) {
      const int n = n0 + wn + j * 16 + l16;
      const float bz = bias[n];
      #pragma unroll
      for (int r = 0; r < 4; ++r) {
        const int m = m0 + wm + i * 16 + quad * 4 + r;
        float v = acc[i][j][r] + bz;
        if (MODE == 0) {
          v = 0.5f * v * (1.0f + erff(v * 0.70710678118654752f));
        } else {
          v += ldf(resid + (size_t)m * N + n);
        }
        stf(out + (size_t)m * N + n, v);
      }
    }
  }
}

extern "C" void kernel_launch(void* const* d_in, const int* in_sizes, int n_in,
                              void* d_out, int out_size, void* d_ws, size_t ws_size,
                              hipStream_t stream) {
  const float* x     = (const float*)d_in[0];
  const float* w1    = (const float*)d_in[1];
  const float* b1    = (const float*)d_in[2];
  const float* w2    = (const float*)d_in[3];
  const float* b2    = (const float*)d_in[4];
  const float* ln1w  = (const float*)d_in[5];
  const float* ln1b  = (const float*)d_in[6];
  const float* ln2w  = (const float*)d_in[7];
  const float* ln2b  = (const float*)d_in[8];
  const float* mlpw1 = (const float*)d_in[9];
  const float* mlpb1 = (const float*)d_in[10];
  const float* mlpw2 = (const float*)d_in[11];
  const float* mlpb2 = (const float*)d_in[12];
  float* out = (float*)d_out;

  const size_t SPA = (size_t)B_ * H_ * W_ * D_;   // 25,165,824 elems
  const size_t FRE = (size_t)B_ * H_ * WF_ * D_;  // 12,779,520 elems
  bf16* ws   = (bf16*)d_ws;
  bf16* bufA = ws;               // xn, later xsp (residual2)
  bf16* Fr   = bufA + SPA;
  bf16* Fi   = Fr + FRE;
  bf16* Gr   = Fi + FRE;
  bf16* Gi   = Gr + FRE;
  bf16* hid  = Fr;                              // GEMM-phase overlays
  bf16* xn2c = Gr;
  bf16* w1t  = xn2c + (size_t)CHTOK_ * D_;
  bf16* w2t  = w1t + (size_t)D_ * HID_;

  const int nspec = B_ * H_ * WF_;  // 16640

  hipLaunchKernelGGL((ln_kernel<float>), dim3(NTOK_), dim3(256), 0, stream, x, ln1w, ln1b, bufA);
  hipLaunchKernelGGL(s1_rfftw, dim3(B_ * H_, D_ / 64), dim3(256), 0, stream, bufA, Fr, Fi);
  hipLaunchKernelGGL(s2_ffth, dim3(B_ * WF_, D_ / 64), dim3(256), 0, stream,
                     Fr, Fi, Gr, Gi, -1.0f);
  hipLaunchKernelGGL(blockmlp_mfma, dim3(nspec / 64, NB_), dim3(256), 0, stream,
                     Gr, Gi, w1, b1, w2, b2);
  hipLaunchKernelGGL(s2_ffth, dim3(B_ * WF_, D_ / 64), dim3(256), 0, stream,
                     Gr, Gi, Fr, Fi, 1.0f);
  hipLaunchKernelGGL(s3_irfftw, dim3(B_ * H_, D_ / 64), dim3(256), 0, stream, Fr, Fi, x, bufA);

  hipLaunchKernelGGL(wtrans_kernel, dim3(HID_ / 32, D_ / 32), dim3(256), 0, stream,
                     mlpw1, w1t, D_, HID_);
  hipLaunchKernelGGL(wtrans_kernel, dim3(D_ / 32, HID_ / 32), dim3(256), 0, stream,
                     mlpw2, w2t, HID_, D_);

  for (int c = 0; c < B_; ++c) {
    const bf16* rs = bufA + (size_t)c * CHTOK_ * D_;
    float* oc = out + (size_t)c * CHTOK_ * D_;
    hipLaunchKernelGGL((ln_kernel<bf16>), dim3(CHTOK_), dim3(256), 0, stream,
                       rs, ln2w, ln2b, xn2c);
    hipLaunchKernelGGL((mfma_gemm_kernel<0, bf16>), dim3(CHTOK_ / 128, HID_ / 128), dim3(256), 0,
                       stream, xn2c, w1t, mlpb1, (const bf16*)nullptr, hid, CHTOK_, HID_, D_);
    hipLaunchKernelGGL((mfma_gemm_kernel<1, float>), dim3(CHTOK_ / 128, D_ / 128), dim3(256), 0,
                       stream, hid, w2t, mlpb2, rs, oc, CHTOK_, D_, HID_);
  }
}

// Round 3
// 1016.080 us; speedup vs baseline: 1.4348x; 1.1190x over previous
//
#include <hip/hip_runtime.h>
#include <hip/hip_bf16.h>
#include <math.h>

#define B_    4
#define H_    64
#define W_    128
#define WF_   65
#define D_    768
#define NB_   8
#define BS_   96
#define HID_  3072
#define NTOK_ 32768
#define CHTOK_ 8192
#define LAM_  0.01f

typedef __hip_bfloat16 bf16;
typedef __attribute__((ext_vector_type(8))) short bf16x8;
typedef __attribute__((ext_vector_type(4))) float f32x4;
typedef unsigned int u32;

__device__ __forceinline__ float ldf(const float* p) { return *p; }
__device__ __forceinline__ float ldf(const bf16* p)  { return __bfloat162float(*p); }
__device__ __forceinline__ void stf(float* p, float v) { *p = v; }
__device__ __forceinline__ void stf(bf16* p, float v)  { *p = __float2bfloat16(v); }

#define GLOAD_LDS16(g, l) \
  __builtin_amdgcn_global_load_lds((const __attribute__((address_space(1))) u32*)(g), \
                                   (__attribute__((address_space(3))) u32*)(l), 16, 0, 0)

// fragment read from LDS row-major [row][Kpad]
#define FRAG(arr, KP, row, kof) (*(const bf16x8*)((arr) + (size_t)(row) * (KP) + (kof)))

// ---- LUT global layout (bf16 elems), banks padded to 4096B multiples ----
// lutS1  @ 0      : C1[80*136], C2[80*136], pad -> 22528 elems (45056 B, 11*4096)
// lutS2m @ 22528  : Tr,Ti,Tn [64*72]*3, pad -> 14336 elems (28672 B, 7*4096)
// lutS2p @ 36864  : same, esign=+1       -> 14336 elems
// lutS3  @ 51200  : Cr[128*104], Ci[128*104] -> 26624 elems (53248 B, 13*4096)
// total 77824 elems (155648 B) — staged in d_out, dead until final GEMMs.
#define LUT_S1_OFF  0
#define LUT_S2M_OFF 22528
#define LUT_S2P_OFF 36864
#define LUT_S3_OFF  51200
#define LUT_TOTAL   77824

__global__ __launch_bounds__(256) void lut_init(bf16* __restrict__ lut) {
  const int idx = blockIdx.x * 256 + threadIdx.x;  // grid 304*256 == 77824 exact
  const float s1 = 0.011048543456039806f;          // 1/sqrt(8192)
  float val = 0.f;
  if (idx < 22528) {                               // s1: C1 then C2
    int a = idx;
    if (a < 21760) {
      bool isC2 = a >= 10880; if (isC2) a -= 10880;
      int f = a / 136, w = a - f * 136;
      if (w < 128) {
        int p = (f * w) & 127;
        float ang = p * 0.04908738521234052f;      // 2*pi/128
        val = isC2 ? -s1 * sinf(ang) : s1 * cosf(ang);
      }
    }
  } else if (idx < 51200) {                        // s2: bank m then bank p
    int a = idx - 22528;
    float esign = -1.f;
    if (a >= 14336) { a -= 14336; esign = 1.f; }
    if (a < 13824) {
      int which = a / 4608; a -= which * 4608;
      int k = a / 72, h = a - k * 72;
      if (h < 64) {
        int p = (k * h) & 63;
        float ang = p * 0.09817477042468103f;      // 2*pi/64
        float c = cosf(ang), s = esign * sinf(ang);
        val = (which == 0) ? c : ((which == 1) ? s : -s);
      }
    }
  } else {                                         // s3: Cr then Ci
    int a = idx - 51200;
    bool isCi = a >= 13312; if (isCi) a -= 13312;
    int w = a / 104, f = a - w * 104;
    if (f < WF_) {
      int p = (f * w) & 127;
      float ang = p * 0.04908738521234052f;
      float al = (f == 0 || f == 64) ? 1.0f : 2.0f;
      val = isCi ? -s1 * al * sinf(ang) : s1 * al * cosf(ang);
    }
  }
  lut[idx] = __float2bfloat16(val);
}

// ---------------- LayerNorm (one block per token, 768 = 3*256) ----------------
template <typename TIN>
__global__ __launch_bounds__(256) void ln_kernel(
    const TIN* __restrict__ x, const float* __restrict__ g,
    const float* __restrict__ bta, bf16* __restrict__ out) {
  __shared__ float sred[8];
  const size_t base = (size_t)blockIdx.x * D_;
  const int t = threadIdx.x;
  float v0 = ldf(x + base + t);
  float v1 = ldf(x + base + t + 256);
  float v2 = ldf(x + base + t + 512);
  float s = v0 + v1 + v2;
  #pragma unroll
  for (int o = 32; o; o >>= 1) s += __shfl_down(s, o, 64);
  int lane = t & 63, wid = t >> 6;
  if (lane == 0) sred[wid] = s;
  __syncthreads();
  if (t == 0) sred[0] = sred[0] + sred[1] + sred[2] + sred[3];
  __syncthreads();
  float mean = sred[0] * (1.0f / D_);
  float d0 = v0 - mean, d1 = v1 - mean, d2 = v2 - mean;
  float q = d0 * d0 + d1 * d1 + d2 * d2;
  #pragma unroll
  for (int o = 32; o; o >>= 1) q += __shfl_down(q, o, 64);
  if (lane == 0) sred[4 + wid] = q;
  __syncthreads();
  if (t == 0) sred[4] = sred[4] + sred[5] + sred[6] + sred[7];
  __syncthreads();
  float rstd = rsqrtf(sred[4] * (1.0f / D_) + 1e-5f);
  stf(out + base + t,       d0 * rstd * g[t]       + bta[t]);
  stf(out + base + t + 256, d1 * rstd * g[t + 256] + bta[t + 256]);
  stf(out + base + t + 512, d2 * rstd * g[t + 512] + bta[t + 512]);
}

// ============ S1: rfft along W as MFMA GEMM. block=(bh, ctile64) ============
// Fr/Fi[(bh,f), c] = sum_w C1/C2[f,w] * xn[(bh,w), c]
__global__ __launch_bounds__(256) void s1_rfftw(
    const bf16* __restrict__ xn, const bf16* __restrict__ lut,
    bf16* __restrict__ fr, bf16* __restrict__ fi) {
  const int KP = 136;  // 128 + pad (272 B rows, 16B aligned)
  __shared__ __align__(16) bf16 sC[22528];       // C1 @0, C2 @10880 (+pad)
  __shared__ __align__(16) bf16 sXt[64 * 136];
  const int t = threadIdx.x;
  const int bh = blockIdx.x;
  const int c0 = blockIdx.y * 64;

  // stage twiddle LUT from global (linear copy, tail-free: 11 * 4096 B)
  #pragma unroll
  for (int it = 0; it < 11; ++it)
    GLOAD_LDS16((const char*)lut + t * 16 + it * 4096, (char*)sC + t * 16 + it * 4096);

  // stage xn tile transposed: sXt[c][w]
  {
    const int cv = (t & 7) * 8;
    #pragma unroll
    for (int rep = 0; rep < 4; ++rep) {
      int w = (t >> 3) + 32 * rep;
      bf16x8 v = *(const bf16x8*)(xn + ((size_t)bh * W_ + w) * D_ + c0 + cv);
      #pragma unroll
      for (int i = 0; i < 8; ++i) sXt[(cv + i) * KP + w] = ((const bf16*)&v)[i];
    }
  }
  __syncthreads();
  const bf16* sC1 = sC;
  const bf16* sC2 = sC + 10880;

  const int wave = t >> 6, lane = t & 63, l16 = lane & 15, quad = lane >> 4;
  const int ni = (wave == 0) ? 2 : 1;
  int itile[2] = {wave, 4};
  f32x4 accR[2][4], accI[2][4];
  #pragma unroll
  for (int ii = 0; ii < 2; ++ii)
    #pragma unroll
    for (int j = 0; j < 4; ++j) { accR[ii][j] = (f32x4){0,0,0,0}; accI[ii][j] = (f32x4){0,0,0,0}; }

  for (int s = 0; s < 4; ++s) {
    const int kof = s * 32 + quad * 8;
    bf16x8 bfrag[4];
    #pragma unroll
    for (int j = 0; j < 4; ++j) bfrag[j] = FRAG(sXt, KP, j * 16 + l16, kof);
    for (int ii = 0; ii < ni; ++ii) {
      const int arow = 16 * itile[ii] + l16;
      bf16x8 a1 = FRAG(sC1, KP, arow, kof);
      bf16x8 a2 = FRAG(sC2, KP, arow, kof);
      #pragma unroll
      for (int j = 0; j < 4; ++j) {
        accR[ii][j] = __builtin_amdgcn_mfma_f32_16x16x32_bf16(a1, bfrag[j], accR[ii][j], 0, 0, 0);
        accI[ii][j] = __builtin_amdgcn_mfma_f32_16x16x32_bf16(a2, bfrag[j], accI[ii][j], 0, 0, 0);
      }
    }
  }
  for (int ii = 0; ii < ni; ++ii) {
    #pragma unroll
    for (int r = 0; r < 4; ++r) {
      const int f = 16 * itile[ii] + quad * 4 + r;
      if (f >= WF_) continue;
      const size_t ob = ((size_t)bh * WF_ + f) * D_ + c0;
      #pragma unroll
      for (int j = 0; j < 4; ++j) {
        fr[ob + j * 16 + l16] = __float2bfloat16(accR[ii][j][r]);
        fi[ob + j * 16 + l16] = __float2bfloat16(accI[ii][j][r]);
      }
    }
  }
}

// ============ S2: FFT along H as MFMA GEMM. block=(b*WF+f, ctile64) ============
// G[k,c] = sum_h T[k,h] * F[h,c],  T from LUT (Tr,Ti,Tn bank for one esign)
__global__ __launch_bounds__(256) void s2_ffth(
    const bf16* __restrict__ inr, const bf16* __restrict__ ini,
    bf16* __restrict__ outr, bf16* __restrict__ outi, const bf16* __restrict__ lut) {
  const int KP = 72;  // 64 + pad (144 B rows)
  __shared__ __align__(16) bf16 sT[14336];       // Tr @0, Ti @4608, Tn @9216 (+pad)
  __shared__ __align__(16) bf16 sFtr[64 * 72];
  __shared__ __align__(16) bf16 sFti[64 * 72];
  const int t = threadIdx.x;
  const int b = blockIdx.x / WF_;
  const int f = blockIdx.x % WF_;
  const int c0 = blockIdx.y * 64;

  // stage twiddle bank (7 * 4096 B, tail-free)
  #pragma unroll
  for (int it = 0; it < 7; ++it)
    GLOAD_LDS16((const char*)lut + t * 16 + it * 4096, (char*)sT + t * 16 + it * 4096);

  {
    const int cv = (t & 7) * 8;
    #pragma unroll
    for (int rep = 0; rep < 2; ++rep) {
      int h = (t >> 3) + 32 * rep;
      size_t g = ((size_t)(b * H_ + h) * WF_ + f) * D_ + c0 + cv;
      bf16x8 vr = *(const bf16x8*)(inr + g);
      bf16x8 vi = *(const bf16x8*)(ini + g);
      #pragma unroll
      for (int i = 0; i < 8; ++i) {
        sFtr[(cv + i) * KP + h] = ((const bf16*)&vr)[i];
        sFti[(cv + i) * KP + h] = ((const bf16*)&vi)[i];
      }
    }
  }
  __syncthreads();
  const bf16* sTr = sT;
  const bf16* sTi = sT + 4608;
  const bf16* sTn = sT + 9216;

  const int wave = t >> 6, lane = t & 63, l16 = lane & 15, quad = lane >> 4;
  f32x4 accR[4], accI[4];
  #pragma unroll
  for (int j = 0; j < 4; ++j) { accR[j] = (f32x4){0,0,0,0}; accI[j] = (f32x4){0,0,0,0}; }

  #pragma unroll
  for (int s = 0; s < 2; ++s) {
    const int kof = s * 32 + quad * 8;
    const int arow = 16 * wave + l16;
    bf16x8 ar = FRAG(sTr, KP, arow, kof);
    bf16x8 ai = FRAG(sTi, KP, arow, kof);
    bf16x8 an = FRAG(sTn, KP, arow, kof);
    #pragma unroll
    for (int j = 0; j < 4; ++j) {
      const int brow = j * 16 + l16;
      bf16x8 br = FRAG(sFtr, KP, brow, kof);
      bf16x8 bi = FRAG(sFti, KP, brow, kof);
      accR[j] = __builtin_amdgcn_mfma_f32_16x16x32_bf16(ar, br, accR[j], 0, 0, 0);
      accR[j] = __builtin_amdgcn_mfma_f32_16x16x32_bf16(an, bi, accR[j], 0, 0, 0);
      accI[j] = __builtin_amdgcn_mfma_f32_16x16x32_bf16(ai, br, accI[j], 0, 0, 0);
      accI[j] = __builtin_amdgcn_mfma_f32_16x16x32_bf16(ar, bi, accI[j], 0, 0, 0);
    }
  }
  #pragma unroll
  for (int r = 0; r < 4; ++r) {
    const int k = 16 * wave + quad * 4 + r;
    const size_t ob = ((size_t)(b * H_ + k) * WF_ + f) * D_ + c0;
    #pragma unroll
    for (int j = 0; j < 4; ++j) {
      outr[ob + j * 16 + l16] = __float2bfloat16(accR[j][r]);
      outi[ob + j * 16 + l16] = __float2bfloat16(accI[j][r]);
    }
  }
}

// ============ S3: irfft along W + residual, MFMA. block=(bh, ctile64) ============
// x[w,c] = sum_f Cr[w,f]*Fr[f,c] + Ci[w,f]*Fi[f,c];  K padded 65->96 (zero rows)
__global__ __launch_bounds__(256) void s3_irfftw(
    const bf16* __restrict__ fr, const bf16* __restrict__ fi,
    const bf16* __restrict__ lut, const float* __restrict__ x0, bf16* __restrict__ xsp) {
  const int KP = 104;  // 96 + pad (208 B rows)
  __shared__ __align__(16) bf16 sC[26624];       // Cr @0, Ci @13312
  __shared__ __align__(16) bf16 sGtr[64 * 104];
  __shared__ __align__(16) bf16 sGti[64 * 104];
  const int t = threadIdx.x;
  const int bh = blockIdx.x;
  const int c0 = blockIdx.y * 64;

  // stage Cr/Ci (13 * 4096 B, exact)
  #pragma unroll
  for (int it = 0; it < 13; ++it)
    GLOAD_LDS16((const char*)lut + t * 16 + it * 4096, (char*)sC + t * 16 + it * 4096);

  {
    const int cv = (t & 7) * 8;
    #pragma unroll
    for (int rep = 0; rep < 2; ++rep) {
      int f = (t >> 3) + 32 * rep;
      size_t g = ((size_t)bh * WF_ + f) * D_ + c0 + cv;
      bf16x8 vr = *(const bf16x8*)(fr + g);
      bf16x8 vi = *(const bf16x8*)(fi + g);
      #pragma unroll
      for (int i = 0; i < 8; ++i) {
        sGtr[(cv + i) * KP + f] = ((const bf16*)&vr)[i];
        sGti[(cv + i) * KP + f] = ((const bf16*)&vi)[i];
      }
    }
    if (t < 8) {  // f = 64 row
      size_t g = ((size_t)bh * WF_ + 64) * D_ + c0 + cv;
      bf16x8 vr = *(const bf16x8*)(fr + g);
      bf16x8 vi = *(const bf16x8*)(fi + g);
      #pragma unroll
      for (int i = 0; i < 8; ++i) {
        sGtr[(cv + i) * KP + 64] = ((const bf16*)&vr)[i];
        sGti[(cv + i) * KP + 64] = ((const bf16*)&vi)[i];
      }
    }
    // zero pad rows f=65..95 (avoid NaN from poisoned LDS)
    const bf16 z = __float2bfloat16(0.f);
    for (int e = t; e < 64 * 31; e += 256) {
      int c = e / 31, f = 65 + (e - (e / 31) * 31);
      sGtr[c * KP + f] = z;
      sGti[c * KP + f] = z;
    }
  }
  __syncthreads();
  const bf16* sCr = sC;
  const bf16* sCi = sC + 13312;

  const int wave = t >> 6, lane = t & 63, l16 = lane & 15, quad = lane >> 4;
  f32x4 acc[2][4];
  #pragma unroll
  for (int ii = 0; ii < 2; ++ii)
    #pragma unroll
    for (int j = 0; j < 4; ++j) acc[ii][j] = (f32x4){0,0,0,0};

  #pragma unroll
  for (int s = 0; s < 3; ++s) {
    const int kof = s * 32 + quad * 8;
    bf16x8 br[4], bi[4];
    #pragma unroll
    for (int j = 0; j < 4; ++j) {
      br[j] = FRAG(sGtr, KP, j * 16 + l16, kof);
      bi[j] = FRAG(sGti, KP, j * 16 + l16, kof);
    }
    #pragma unroll
    for (int ii = 0; ii < 2; ++ii) {
      const int arow = 16 * (wave + 4 * ii) + l16;
      bf16x8 a1 = FRAG(sCr, KP, arow, kof);
      bf16x8 a2 = FRAG(sCi, KP, arow, kof);
      #pragma unroll
      for (int j = 0; j < 4; ++j) {
        acc[ii][j] = __builtin_amdgcn_mfma_f32_16x16x32_bf16(a1, br[j], acc[ii][j], 0, 0, 0);
        acc[ii][j] = __builtin_amdgcn_mfma_f32_16x16x32_bf16(a2, bi[j], acc[ii][j], 0, 0, 0);
      }
    }
  }
  #pragma unroll
  for (int ii = 0; ii < 2; ++ii) {
    #pragma unroll
    for (int r = 0; r < 4; ++r) {
      const int w = 16 * (wave + 4 * ii) + quad * 4 + r;
      const size_t ob = ((size_t)bh * W_ + w) * D_ + c0;
      #pragma unroll
      for (int j = 0; j < 4; ++j) {
        const size_t o = ob + j * 16 + l16;
        xsp[o] = __float2bfloat16(acc[ii][j][r] + x0[o]);
      }
    }
  }
}

// ============ block-diagonal complex MLP as MFMA, in place ============
__global__ __launch_bounds__(256) void blockmlp_mfma(
    bf16* __restrict__ gr, bf16* __restrict__ gi,
    const float* __restrict__ w1, const float* __restrict__ b1,
    const float* __restrict__ w2, const float* __restrict__ b2) {
  const int KP = 104;  // 96 + pad (208 B rows: 13x16B slots -> conflict-free b128)
  __shared__ __align__(16) bf16 sA[128 * 104];
  __shared__ __align__(16) bf16 sW[96 * 104];
  const int t = threadIdx.x;
  const int p0 = blockIdx.x * 64;
  const int nb = blockIdx.y;
  const int cbase = nb * BS_;

  // ---- stage u,v (64 rows x 12 bf16x8 vectors each) ----
  #pragma unroll
  for (int it = 0; it < 3; ++it) {
    int task = t + 256 * it;          // 0..767
    int r = task / 12, jv = task - r * 12;
    size_t g = (size_t)(p0 + r) * D_ + cbase + jv * 8;
    bf16x8 vr = *(const bf16x8*)(gr + g);
    bf16x8 vi = *(const bf16x8*)(gi + g);
    bf16x8 u8, v8;
    #pragma unroll
    for (int i = 0; i < 8; ++i) {
      float xr = __bfloat162float(((const bf16*)&vr)[i]);
      float xi = __bfloat162float(((const bf16*)&vi)[i]);
      ((bf16*)&u8)[i] = __float2bfloat16(xr - xi);
      ((bf16*)&v8)[i] = __float2bfloat16(xr + xi);
    }
    *(bf16x8*)(sA + r * KP + jv * 8) = u8;
    *(bf16x8*)(sA + (64 + r) * KP + jv * 8) = v8;
  }
  // ---- stage W1^T: sW[m][j] = w1[nb][j][m] ----
  {
    const float* wsrc = w1 + nb * BS_ * BS_;
    #pragma unroll
    for (int it = 0; it < 9; ++it) {
      int e4 = t + 256 * it;          // 0..2303 tasks of 4 elems
      int j = e4 / 24, m4 = (e4 - j * 24) * 4;
      float4 ld = *(const float4*)(wsrc + j * 96 + m4);
      sW[(m4 + 0) * KP + j] = __float2bfloat16(ld.x);
      sW[(m4 + 1) * KP + j] = __float2bfloat16(ld.y);
      sW[(m4 + 2) * KP + j] = __float2bfloat16(ld.z);
      sW[(m4 + 3) * KP + j] = __float2bfloat16(ld.w);
    }
  }
  __syncthreads();

  const int wave = t >> 6, lane = t & 63, l16 = lane & 15, quad = lane >> 4;
  f32x4 accU[6], accV[6];
  #pragma unroll
  for (int n = 0; n < 6; ++n) { accU[n] = (f32x4){0,0,0,0}; accV[n] = (f32x4){0,0,0,0}; }

  #pragma unroll
  for (int s = 0; s < 3; ++s) {
    const int kof = s * 32 + quad * 8;
    bf16x8 au = FRAG(sA, KP, wave * 16 + l16, kof);
    bf16x8 av = FRAG(sA, KP, 64 + wave * 16 + l16, kof);
    bf16x8 bw[6];
    #pragma unroll
    for (int n = 0; n < 6; ++n) bw[n] = FRAG(sW, KP, n * 16 + l16, kof);
    #pragma unroll
    for (int n = 0; n < 6; ++n) {
      accU[n] = __builtin_amdgcn_mfma_f32_16x16x32_bf16(au, bw[n], accU[n], 0, 0, 0);
      accV[n] = __builtin_amdgcn_mfma_f32_16x16x32_bf16(av, bw[n], accV[n], 0, 0, 0);
    }
  }
  __syncthreads();  // all layer-1 reads of sA/sW complete

  // ---- re-stage W2^T (overwrites sW) ----
  {
    const float* wsrc = w2 + nb * BS_ * BS_;
    #pragma unroll
    for (int it = 0; it < 9; ++it) {
      int e4 = t + 256 * it;
      int j = e4 / 24, m4 = (e4 - j * 24) * 4;
      float4 ld = *(const float4*)(wsrc + j * 96 + m4);
      sW[(m4 + 0) * KP + j] = __float2bfloat16(ld.x);
      sW[(m4 + 1) * KP + j] = __float2bfloat16(ld.y);
      sW[(m4 + 2) * KP + j] = __float2bfloat16(ld.z);
      sW[(m4 + 3) * KP + j] = __float2bfloat16(ld.w);
    }
  }
  // ---- relu + combine into p,q; write back into sA ----
  #pragma unroll
  for (int n = 0; n < 6; ++n) {
    const float bias = b1[cbase + n * 16 + l16];
    #pragma unroll
    for (int r = 0; r < 4; ++r) {
      float o1r = fmaxf(accU[n][r] + bias, 0.0f);
      float o1i = fmaxf(accV[n][r] + bias, 0.0f);
      const int row = wave * 16 + quad * 4 + r;
      sA[row * KP + n * 16 + l16]        = __float2bfloat16(o1r - o1i);  // p
      sA[(64 + row) * KP + n * 16 + l16] = __float2bfloat16(o1r + o1i);  // q
    }
  }
  __syncthreads();

  // ---- layer 2: accP = p @ W2, accQ = q @ W2 ----
  #pragma unroll
  for (int n = 0; n < 6; ++n) { accU[n] = (f32x4){0,0,0,0}; accV[n] = (f32x4){0,0,0,0}; }
  #pragma unroll
  for (int s = 0; s < 3; ++s) {
    const int kof = s * 32 + quad * 8;
    bf16x8 ap = FRAG(sA, KP, wave * 16 + l16, kof);
    bf16x8 aq = FRAG(sA, KP, 64 + wave * 16 + l16, kof);
    bf16x8 bw[6];
    #pragma unroll
    for (int n = 0; n < 6; ++n) bw[n] = FRAG(sW, KP, n * 16 + l16, kof);
    #pragma unroll
    for (int n = 0; n < 6; ++n) {
      accU[n] = __builtin_amdgcn_mfma_f32_16x16x32_bf16(ap, bw[n], accU[n], 0, 0, 0);
      accV[n] = __builtin_amdgcn_mfma_f32_16x16x32_bf16(aq, bw[n], accV[n], 0, 0, 0);
    }
  }

  // ---- bias + softshrink + store ----
  #pragma unroll
  for (int n = 0; n < 6; ++n) {
    const float bias = b2[cbase + n * 16 + l16];
    #pragma unroll
    for (int r = 0; r < 4; ++r) {
      const int row = wave * 16 + quad * 4 + r;
      float o2r = accU[n][r] + bias;
      float o2i = accV[n][r] + bias;
      o2r = (o2r > LAM_) ? (o2r - LAM_) : ((o2r < -LAM_) ? (o2r + LAM_) : 0.0f);
      o2i = (o2i > LAM_) ? (o2i - LAM_) : ((o2i < -LAM_) ? (o2i + LAM_) : 0.0f);
      const size_t o = (size_t)(p0 + row) * D_ + cbase + n * 16 + l16;
      gr[o] = __float2bfloat16(o2r);
      gi[o] = __float2bfloat16(o2i);
    }
  }
}

// ---------------- weight transpose+cast: W (K x N fp32) -> Wt (N x K bf16) ----
__global__ __launch_bounds__(256) void wtrans_kernel(
    const float* __restrict__ Wm, bf16* __restrict__ Wt, int K, int N) {
  __shared__ float tile[32][33];
  const int n0 = blockIdx.x * 32;
  const int k0 = blockIdx.y * 32;
  const int tx = threadIdx.x & 31;
  const int ty = threadIdx.x >> 5;   // 0..7
  #pragma unroll
  for (int r = 0; r < 32; r += 8)
    tile[ty + r][tx] = Wm[(size_t)(k0 + ty + r) * N + n0 + tx];
  __syncthreads();
  #pragma unroll
  for (int r = 0; r < 32; r += 8)
    Wt[(size_t)(n0 + ty + r) * K + k0 + tx] = __float2bfloat16(tile[tx][ty + r]);
}

// ---------------- MFMA GEMM: out = act(A @ Bt^T + bias) [+ resid] ----------------
template <int MODE, typename TOUT>
__global__ __launch_bounds__(256) void mfma_gemm_kernel(
    const bf16* __restrict__ A, const bf16* __restrict__ Bt,
    const float* __restrict__ bias, const bf16* __restrict__ resid,
    TOUT* __restrict__ out, int M, int N, int K) {
  __shared__ __align__(16) bf16 As[128 * 32];
  __shared__ __align__(16) bf16 Bs[128 * 32];
  const int t = threadIdx.x;
  const int m0 = blockIdx.x * 128;
  const int n0 = blockIdx.y * 128;
  const int wave = t >> 6;
  const int lane = t & 63;
  const int wm = (wave & 1) * 64;
  const int wn = (wave >> 1) * 64;
  const int l16 = lane & 15;
  const int quad = lane >> 4;

  const int srow = t >> 2;
  const int skof = (t & 3) * 8;
  const bf16* Ag0 = A + (size_t)(m0 + srow) * K + skof;
  const bf16* Ag1 = A + (size_t)(m0 + 64 + srow) * K + skof;
  const bf16* Bg0 = Bt + (size_t)(n0 + srow) * K + skof;
  const bf16* Bg1 = Bt + (size_t)(n0 + 64 + srow) * K + skof;
  bf16* Al0 = As + t * 8;
  bf16* Al1 = As + 2048 + t * 8;
  bf16* Bl0 = Bs + t * 8;
  bf16* Bl1 = Bs + 2048 + t * 8;

  f32x4 acc[4][4];
  #pragma unroll
  for (int i = 0; i < 4; ++i)
    #pragma unroll
    for (int j = 0; j < 4; ++j) acc[i][j] = (f32x4){0.f, 0.f, 0.f, 0.f};

  for (int k0 = 0; k0 < K; k0 += 32) {
    __syncthreads();
    GLOAD_LDS16(Ag0 + k0, Al0);
    GLOAD_LDS16(Ag1 + k0, Al1);
    GLOAD_LDS16(Bg0 + k0, Bl0);
    GLOAD_LDS16(Bg1 + k0, Bl1);
    __syncthreads();
    bf16x8 af[4], bfr[4];
    #pragma unroll
    for (int i = 0; i < 4; ++i)
      af[i] = *(const bf16x8*)(As + (wm + i * 16 + l16) * 32 + quad * 8);
    #pragma unroll
    for (int j = 0; j < 4; ++j)
      bfr[j] = *(const bf16x8*)(Bs + (wn + j * 16 + l16) * 32 + quad * 8);
    #pragma unroll
    for (int i = 0; i < 4; ++i)
      #pragma unroll
      for (int j = 0; j < 4; ++j)
        acc[i][j] = __builtin_amdgcn_mfma_f32_16x16x32_bf16(af[i], bfr[j], acc[i][j], 0, 0, 0);
  }

  #pragma unroll
  for (int i = 0; i < 4; ++i) {
    #pragma unroll
    for (int j = 0; j < 4; ++j) {
      const int n = n0 + wn + j * 16 + l16;
      const float bz = bias[n];
      #pragma unroll
      for (int r = 0; r < 4; ++r) {
        const int m = m0 + wm + i * 16 + quad * 4 + r;
        float v = acc[i][j][r] + bz;
        if (MODE == 0) {
          v = 0.5f * v * (1.0f + erff(v * 0.70710678118654752f));
        } else {
          v += ldf(resid + (size_t)m * N + n);
        }
        stf(out + (size_t)m * N + n, v);
      }
    }
  }
}

extern "C" void kernel_launch(void* const* d_in, const int* in_sizes, int n_in,
                              void* d_out, int out_size, void* d_ws, size_t ws_size,
                              hipStream_t stream) {
  const float* x     = (const float*)d_in[0];
  const float* w1    = (const float*)d_in[1];
  const float* b1    = (const float*)d_in[2];
  const float* w2    = (const float*)d_in[3];
  const float* b2    = (const float*)d_in[4];
  const float* ln1w  = (const float*)d_in[5];
  const float* ln1b  = (const float*)d_in[6];
  const float* ln2w  = (const float*)d_in[7];
  const float* ln2b  = (const float*)d_in[8];
  const float* mlpw1 = (const float*)d_in[9];
  const float* mlpb1 = (const float*)d_in[10];
  const float* mlpw2 = (const float*)d_in[11];
  const float* mlpb2 = (const float*)d_in[12];
  float* out = (float*)d_out;

  const size_t SPA = (size_t)B_ * H_ * W_ * D_;   // 25,165,824 elems
  const size_t FRE = (size_t)B_ * H_ * WF_ * D_;  // 12,779,520 elems
  bf16* ws   = (bf16*)d_ws;
  bf16* bufA = ws;               // xn, later xsp (residual2)
  bf16* Fr   = bufA + SPA;
  bf16* Fi   = Fr + FRE;
  bf16* Gr   = Fi + FRE;
  bf16* Gi   = Gr + FRE;
  bf16* hid  = Fr;                              // GEMM-phase overlays
  bf16* xn2c = Gr;
  bf16* w1t  = xn2c + (size_t)CHTOK_ * D_;
  bf16* w2t  = w1t + (size_t)D_ * HID_;

  // twiddle LUTs live in d_out (dead until the final GEMM phase writes it)
  bf16* lut = (bf16*)d_out;

  const int nspec = B_ * H_ * WF_;  // 16640

  hipLaunchKernelGGL(lut_init, dim3(LUT_TOTAL / 256), dim3(256), 0, stream, lut);
  hipLaunchKernelGGL((ln_kernel<float>), dim3(NTOK_), dim3(256), 0, stream, x, ln1w, ln1b, bufA);
  hipLaunchKernelGGL(s1_rfftw, dim3(B_ * H_, D_ / 64), dim3(256), 0, stream,
                     bufA, lut + LUT_S1_OFF, Fr, Fi);
  hipLaunchKernelGGL(s2_ffth, dim3(B_ * WF_, D_ / 64), dim3(256), 0, stream,
                     Fr, Fi, Gr, Gi, lut + LUT_S2M_OFF);
  hipLaunchKernelGGL(blockmlp_mfma, dim3(nspec / 64, NB_), dim3(256), 0, stream,
                     Gr, Gi, w1, b1, w2, b2);
  hipLaunchKernelGGL(s2_ffth, dim3(B_ * WF_, D_ / 64), dim3(256), 0, stream,
                     Gr, Gi, Fr, Fi, lut + LUT_S2P_OFF);
  hipLaunchKernelGGL(s3_irfftw, dim3(B_ * H_, D_ / 64), dim3(256), 0, stream,
                     Fr, Fi, lut + LUT_S3_OFF, x, bufA);

  hipLaunchKernelGGL(wtrans_kernel, dim3(HID_ / 32, D_ / 32), dim3(256), 0, stream,
                     mlpw1, w1t, D_, HID_);
  hipLaunchKernelGGL(wtrans_kernel, dim3(D_ / 32, HID_ / 32), dim3(256), 0, stream,
                     mlpw2, w2t, HID_, D_);

  for (int c = 0; c < B_; ++c) {
    const bf16* rs = bufA + (size_t)c * CHTOK_ * D_;
    float* oc = out + (size_t)c * CHTOK_ * D_;
    hipLaunchKernelGGL((ln_kernel<bf16>), dim3(CHTOK_), dim3(256), 0, stream,
                       rs, ln2w, ln2b, xn2c);
    hipLaunchKernelGGL((mfma_gemm_kernel<0, bf16>), dim3(CHTOK_ / 128, HID_ / 128), dim3(256), 0,
                       stream, xn2c, w1t, mlpb1, (const bf16*)nullptr, hid, CHTOK_, HID_, D_);
    hipLaunchKernelGGL((mfma_gemm_kernel<1, float>), dim3(CHTOK_ / 128, D_ / 128), dim3(256), 0,
                       stream, hid, w2t, mlpb2, rs, oc, CHTOK_, D_, HID_);
  }
}

// Round 4
// 945.272 us; speedup vs baseline: 1.5423x; 1.0749x over previous
//
#include <hip/hip_runtime.h>
#include <hip/hip_bf16.h>
#include <math.h>

#define B_    4
#define H_    64
#define W_    128
#define WF_   65
#define D_    768
#define NB_   8
#define BS_   96
#define HID_  3072
#define NTOK_ 32768
#define CHTOK_ 8192
#define LAM_  0.01f

typedef __hip_bfloat16 bf16;
typedef __attribute__((ext_vector_type(8))) short bf16x8;
typedef __attribute__((ext_vector_type(4))) float f32x4;
typedef unsigned int u32;

__device__ __forceinline__ float ldf(const float* p) { return *p; }
__device__ __forceinline__ float ldf(const bf16* p)  { return __bfloat162float(*p); }
__device__ __forceinline__ void stf(float* p, float v) { *p = v; }
__device__ __forceinline__ void stf(bf16* p, float v)  { *p = __float2bfloat16(v); }

#define GLOAD_LDS16(g, l) \
  __builtin_amdgcn_global_load_lds((const __attribute__((address_space(1))) u32*)(g), \
                                   (__attribute__((address_space(3))) u32*)(l), 16, 0, 0)

// fragment read from LDS row-major [row][Kpad]
#define FRAG(arr, KP, row, kof) (*(const bf16x8*)((arr) + (size_t)(row) * (KP) + (kof)))

// ---- LUT global layout (bf16 elems), banks padded to 4096B multiples ----
#define LUT_S1_OFF  0
#define LUT_S2M_OFF 22528
#define LUT_S2P_OFF 36864
#define LUT_S3_OFF  51200
#define LUT_TOTAL   77824

__global__ __launch_bounds__(256) void lut_init(bf16* __restrict__ lut) {
  const int idx = blockIdx.x * 256 + threadIdx.x;  // grid 304*256 == 77824 exact
  const float s1 = 0.011048543456039806f;          // 1/sqrt(8192)
  float val = 0.f;
  if (idx < 22528) {                               // s1: C1 then C2
    int a = idx;
    if (a < 21760) {
      bool isC2 = a >= 10880; if (isC2) a -= 10880;
      int f = a / 136, w = a - f * 136;
      if (w < 128) {
        int p = (f * w) & 127;
        float ang = p * 0.04908738521234052f;      // 2*pi/128
        val = isC2 ? -s1 * sinf(ang) : s1 * cosf(ang);
      }
    }
  } else if (idx < 51200) {                        // s2: bank m then bank p
    int a = idx - 22528;
    float esign = -1.f;
    if (a >= 14336) { a -= 14336; esign = 1.f; }
    if (a < 13824) {
      int which = a / 4608; a -= which * 4608;
      int k = a / 72, h = a - k * 72;
      if (h < 64) {
        int p = (k * h) & 63;
        float ang = p * 0.09817477042468103f;      // 2*pi/64
        float c = cosf(ang), s = esign * sinf(ang);
        val = (which == 0) ? c : ((which == 1) ? s : -s);
      }
    }
  } else {                                         // s3: Cr then Ci
    int a = idx - 51200;
    bool isCi = a >= 13312; if (isCi) a -= 13312;
    int w = a / 104, f = a - w * 104;
    if (f < WF_) {
      int p = (f * w) & 127;
      float ang = p * 0.04908738521234052f;
      float al = (f == 0 || f == 64) ? 1.0f : 2.0f;
      val = isCi ? -s1 * al * sinf(ang) : s1 * al * cosf(ang);
    }
  }
  lut[idx] = __float2bfloat16(val);
}

// ---------------- LayerNorm (one block per token, 768 = 3*256) ----------------
template <typename TIN>
__global__ __launch_bounds__(256) void ln_kernel(
    const TIN* __restrict__ x, const float* __restrict__ g,
    const float* __restrict__ bta, bf16* __restrict__ out) {
  __shared__ float sred[8];
  const size_t base = (size_t)blockIdx.x * D_;
  const int t = threadIdx.x;
  float v0 = ldf(x + base + t);
  float v1 = ldf(x + base + t + 256);
  float v2 = ldf(x + base + t + 512);
  float s = v0 + v1 + v2;
  #pragma unroll
  for (int o = 32; o; o >>= 1) s += __shfl_down(s, o, 64);
  int lane = t & 63, wid = t >> 6;
  if (lane == 0) sred[wid] = s;
  __syncthreads();
  if (t == 0) sred[0] = sred[0] + sred[1] + sred[2] + sred[3];
  __syncthreads();
  float mean = sred[0] * (1.0f / D_);
  float d0 = v0 - mean, d1 = v1 - mean, d2 = v2 - mean;
  float q = d0 * d0 + d1 * d1 + d2 * d2;
  #pragma unroll
  for (int o = 32; o; o >>= 1) q += __shfl_down(q, o, 64);
  if (lane == 0) sred[4 + wid] = q;
  __syncthreads();
  if (t == 0) sred[4] = sred[4] + sred[5] + sred[6] + sred[7];
  __syncthreads();
  float rstd = rsqrtf(sred[4] * (1.0f / D_) + 1e-5f);
  stf(out + base + t,       d0 * rstd * g[t]       + bta[t]);
  stf(out + base + t + 256, d1 * rstd * g[t + 256] + bta[t + 256]);
  stf(out + base + t + 512, d2 * rstd * g[t + 512] + bta[t + 512]);
}

// ============ S1: rfft along W as MFMA GEMM. block=(bh, ctile64) ============
__global__ __launch_bounds__(256) void s1_rfftw(
    const bf16* __restrict__ xn, const bf16* __restrict__ lut,
    bf16* __restrict__ fr, bf16* __restrict__ fi) {
  const int KP = 136;  // 128 + pad (272 B rows, 16B aligned)
  __shared__ __align__(16) bf16 sC[22528];       // C1 @0, C2 @10880 (+pad)
  __shared__ __align__(16) bf16 sXt[64 * 136];
  const int t = threadIdx.x;
  const int bh = blockIdx.x;
  const int c0 = blockIdx.y * 64;

  #pragma unroll
  for (int it = 0; it < 11; ++it)
    GLOAD_LDS16((const char*)lut + t * 16 + it * 4096, (char*)sC + t * 16 + it * 4096);

  {
    const int cv = (t & 7) * 8;
    #pragma unroll
    for (int rep = 0; rep < 4; ++rep) {
      int w = (t >> 3) + 32 * rep;
      bf16x8 v = *(const bf16x8*)(xn + ((size_t)bh * W_ + w) * D_ + c0 + cv);
      #pragma unroll
      for (int i = 0; i < 8; ++i) sXt[(cv + i) * KP + w] = ((const bf16*)&v)[i];
    }
  }
  __syncthreads();
  const bf16* sC1 = sC;
  const bf16* sC2 = sC + 10880;

  const int wave = t >> 6, lane = t & 63, l16 = lane & 15, quad = lane >> 4;
  const int ni = (wave == 0) ? 2 : 1;
  int itile[2] = {wave, 4};
  f32x4 accR[2][4], accI[2][4];
  #pragma unroll
  for (int ii = 0; ii < 2; ++ii)
    #pragma unroll
    for (int j = 0; j < 4; ++j) { accR[ii][j] = (f32x4){0,0,0,0}; accI[ii][j] = (f32x4){0,0,0,0}; }

  for (int s = 0; s < 4; ++s) {
    const int kof = s * 32 + quad * 8;
    bf16x8 bfrag[4];
    #pragma unroll
    for (int j = 0; j < 4; ++j) bfrag[j] = FRAG(sXt, KP, j * 16 + l16, kof);
    for (int ii = 0; ii < ni; ++ii) {
      const int arow = 16 * itile[ii] + l16;
      bf16x8 a1 = FRAG(sC1, KP, arow, kof);
      bf16x8 a2 = FRAG(sC2, KP, arow, kof);
      #pragma unroll
      for (int j = 0; j < 4; ++j) {
        accR[ii][j] = __builtin_amdgcn_mfma_f32_16x16x32_bf16(a1, bfrag[j], accR[ii][j], 0, 0, 0);
        accI[ii][j] = __builtin_amdgcn_mfma_f32_16x16x32_bf16(a2, bfrag[j], accI[ii][j], 0, 0, 0);
      }
    }
  }
  for (int ii = 0; ii < ni; ++ii) {
    #pragma unroll
    for (int r = 0; r < 4; ++r) {
      const int f = 16 * itile[ii] + quad * 4 + r;
      if (f >= WF_) continue;
      const size_t ob = ((size_t)bh * WF_ + f) * D_ + c0;
      #pragma unroll
      for (int j = 0; j < 4; ++j) {
        fr[ob + j * 16 + l16] = __float2bfloat16(accR[ii][j][r]);
        fi[ob + j * 16 + l16] = __float2bfloat16(accI[ii][j][r]);
      }
    }
  }
}

// ============ S2: FFT along H as MFMA GEMM. block=(b*WF+f, ctile64) ============
__global__ __launch_bounds__(256) void s2_ffth(
    const bf16* __restrict__ inr, const bf16* __restrict__ ini,
    bf16* __restrict__ outr, bf16* __restrict__ outi, const bf16* __restrict__ lut) {
  const int KP = 72;  // 64 + pad (144 B rows)
  __shared__ __align__(16) bf16 sT[14336];       // Tr @0, Ti @4608, Tn @9216 (+pad)
  __shared__ __align__(16) bf16 sFtr[64 * 72];
  __shared__ __align__(16) bf16 sFti[64 * 72];
  const int t = threadIdx.x;
  const int b = blockIdx.x / WF_;
  const int f = blockIdx.x % WF_;
  const int c0 = blockIdx.y * 64;

  #pragma unroll
  for (int it = 0; it < 7; ++it)
    GLOAD_LDS16((const char*)lut + t * 16 + it * 4096, (char*)sT + t * 16 + it * 4096);

  {
    const int cv = (t & 7) * 8;
    #pragma unroll
    for (int rep = 0; rep < 2; ++rep) {
      int h = (t >> 3) + 32 * rep;
      size_t g = ((size_t)(b * H_ + h) * WF_ + f) * D_ + c0 + cv;
      bf16x8 vr = *(const bf16x8*)(inr + g);
      bf16x8 vi = *(const bf16x8*)(ini + g);
      #pragma unroll
      for (int i = 0; i < 8; ++i) {
        sFtr[(cv + i) * KP + h] = ((const bf16*)&vr)[i];
        sFti[(cv + i) * KP + h] = ((const bf16*)&vi)[i];
      }
    }
  }
  __syncthreads();
  const bf16* sTr = sT;
  const bf16* sTi = sT + 4608;
  const bf16* sTn = sT + 9216;

  const int wave = t >> 6, lane = t & 63, l16 = lane & 15, quad = lane >> 4;
  f32x4 accR[4], accI[4];
  #pragma unroll
  for (int j = 0; j < 4; ++j) { accR[j] = (f32x4){0,0,0,0}; accI[j] = (f32x4){0,0,0,0}; }

  #pragma unroll
  for (int s = 0; s < 2; ++s) {
    const int kof = s * 32 + quad * 8;
    const int arow = 16 * wave + l16;
    bf16x8 ar = FRAG(sTr, KP, arow, kof);
    bf16x8 ai = FRAG(sTi, KP, arow, kof);
    bf16x8 an = FRAG(sTn, KP, arow, kof);
    #pragma unroll
    for (int j = 0; j < 4; ++j) {
      const int brow = j * 16 + l16;
      bf16x8 br = FRAG(sFtr, KP, brow, kof);
      bf16x8 bi = FRAG(sFti, KP, brow, kof);
      accR[j] = __builtin_amdgcn_mfma_f32_16x16x32_bf16(ar, br, accR[j], 0, 0, 0);
      accR[j] = __builtin_amdgcn_mfma_f32_16x16x32_bf16(an, bi, accR[j], 0, 0, 0);
      accI[j] = __builtin_amdgcn_mfma_f32_16x16x32_bf16(ai, br, accI[j], 0, 0, 0);
      accI[j] = __builtin_amdgcn_mfma_f32_16x16x32_bf16(ar, bi, accI[j], 0, 0, 0);
    }
  }
  #pragma unroll
  for (int r = 0; r < 4; ++r) {
    const int k = 16 * wave + quad * 4 + r;
    const size_t ob = ((size_t)(b * H_ + k) * WF_ + f) * D_ + c0;
    #pragma unroll
    for (int j = 0; j < 4; ++j) {
      outr[ob + j * 16 + l16] = __float2bfloat16(accR[j][r]);
      outi[ob + j * 16 + l16] = __float2bfloat16(accI[j][r]);
    }
  }
}

// ============ S3: irfft along W + residual, MFMA. block=(bh, ctile64) ============
__global__ __launch_bounds__(256) void s3_irfftw(
    const bf16* __restrict__ fr, const bf16* __restrict__ fi,
    const bf16* __restrict__ lut, const float* __restrict__ x0, bf16* __restrict__ xsp) {
  const int KP = 104;  // 96 + pad (208 B rows)
  __shared__ __align__(16) bf16 sC[26624];       // Cr @0, Ci @13312
  __shared__ __align__(16) bf16 sGtr[64 * 104];
  __shared__ __align__(16) bf16 sGti[64 * 104];
  const int t = threadIdx.x;
  const int bh = blockIdx.x;
  const int c0 = blockIdx.y * 64;

  #pragma unroll
  for (int it = 0; it < 13; ++it)
    GLOAD_LDS16((const char*)lut + t * 16 + it * 4096, (char*)sC + t * 16 + it * 4096);

  {
    const int cv = (t & 7) * 8;
    #pragma unroll
    for (int rep = 0; rep < 2; ++rep) {
      int f = (t >> 3) + 32 * rep;
      size_t g = ((size_t)bh * WF_ + f) * D_ + c0 + cv;
      bf16x8 vr = *(const bf16x8*)(fr + g);
      bf16x8 vi = *(const bf16x8*)(fi + g);
      #pragma unroll
      for (int i = 0; i < 8; ++i) {
        sGtr[(cv + i) * KP + f] = ((const bf16*)&vr)[i];
        sGti[(cv + i) * KP + f] = ((const bf16*)&vi)[i];
      }
    }
    if (t < 8) {  // f = 64 row
      size_t g = ((size_t)bh * WF_ + 64) * D_ + c0 + cv;
      bf16x8 vr = *(const bf16x8*)(fr + g);
      bf16x8 vi = *(const bf16x8*)(fi + g);
      #pragma unroll
      for (int i = 0; i < 8; ++i) {
        sGtr[(cv + i) * KP + 64] = ((const bf16*)&vr)[i];
        sGti[(cv + i) * KP + 64] = ((const bf16*)&vi)[i];
      }
    }
    const bf16 z = __float2bfloat16(0.f);
    for (int e = t; e < 64 * 31; e += 256) {
      int c = e / 31, f = 65 + (e - (e / 31) * 31);
      sGtr[c * KP + f] = z;
      sGti[c * KP + f] = z;
    }
  }
  __syncthreads();
  const bf16* sCr = sC;
  const bf16* sCi = sC + 13312;

  const int wave = t >> 6, lane = t & 63, l16 = lane & 15, quad = lane >> 4;
  f32x4 acc[2][4];
  #pragma unroll
  for (int ii = 0; ii < 2; ++ii)
    #pragma unroll
    for (int j = 0; j < 4; ++j) acc[ii][j] = (f32x4){0,0,0,0};

  #pragma unroll
  for (int s = 0; s < 3; ++s) {
    const int kof = s * 32 + quad * 8;
    bf16x8 br[4], bi[4];
    #pragma unroll
    for (int j = 0; j < 4; ++j) {
      br[j] = FRAG(sGtr, KP, j * 16 + l16, kof);
      bi[j] = FRAG(sGti, KP, j * 16 + l16, kof);
    }
    #pragma unroll
    for (int ii = 0; ii < 2; ++ii) {
      const int arow = 16 * (wave + 4 * ii) + l16;
      bf16x8 a1 = FRAG(sCr, KP, arow, kof);
      bf16x8 a2 = FRAG(sCi, KP, arow, kof);
      #pragma unroll
      for (int j = 0; j < 4; ++j) {
        acc[ii][j] = __builtin_amdgcn_mfma_f32_16x16x32_bf16(a1, br[j], acc[ii][j], 0, 0, 0);
        acc[ii][j] = __builtin_amdgcn_mfma_f32_16x16x32_bf16(a2, bi[j], acc[ii][j], 0, 0, 0);
      }
    }
  }
  #pragma unroll
  for (int ii = 0; ii < 2; ++ii) {
    #pragma unroll
    for (int r = 0; r < 4; ++r) {
      const int w = 16 * (wave + 4 * ii) + quad * 4 + r;
      const size_t ob = ((size_t)bh * W_ + w) * D_ + c0;
      #pragma unroll
      for (int j = 0; j < 4; ++j) {
        const size_t o = ob + j * 16 + l16;
        xsp[o] = __float2bfloat16(acc[ii][j][r] + x0[o]);
      }
    }
  }
}

// ============ block-diagonal complex MLP as MFMA, in place ============
__global__ __launch_bounds__(256) void blockmlp_mfma(
    bf16* __restrict__ gr, bf16* __restrict__ gi,
    const float* __restrict__ w1, const float* __restrict__ b1,
    const float* __restrict__ w2, const float* __restrict__ b2) {
  const int KP = 104;  // 96 + pad (208 B rows: 13x16B slots -> conflict-free b128)
  __shared__ __align__(16) bf16 sA[128 * 104];
  __shared__ __align__(16) bf16 sW[96 * 104];
  const int t = threadIdx.x;
  const int p0 = blockIdx.x * 64;
  const int nb = blockIdx.y;
  const int cbase = nb * BS_;

  #pragma unroll
  for (int it = 0; it < 3; ++it) {
    int task = t + 256 * it;          // 0..767
    int r = task / 12, jv = task - r * 12;
    size_t g = (size_t)(p0 + r) * D_ + cbase + jv * 8;
    bf16x8 vr = *(const bf16x8*)(gr + g);
    bf16x8 vi = *(const bf16x8*)(gi + g);
    bf16x8 u8, v8;
    #pragma unroll
    for (int i = 0; i < 8; ++i) {
      float xr = __bfloat162float(((const bf16*)&vr)[i]);
      float xi = __bfloat162float(((const bf16*)&vi)[i]);
      ((bf16*)&u8)[i] = __float2bfloat16(xr - xi);
      ((bf16*)&v8)[i] = __float2bfloat16(xr + xi);
    }
    *(bf16x8*)(sA + r * KP + jv * 8) = u8;
    *(bf16x8*)(sA + (64 + r) * KP + jv * 8) = v8;
  }
  {
    const float* wsrc = w1 + nb * BS_ * BS_;
    #pragma unroll
    for (int it = 0; it < 9; ++it) {
      int e4 = t + 256 * it;          // 0..2303 tasks of 4 elems
      int j = e4 / 24, m4 = (e4 - j * 24) * 4;
      float4 ld = *(const float4*)(wsrc + j * 96 + m4);
      sW[(m4 + 0) * KP + j] = __float2bfloat16(ld.x);
      sW[(m4 + 1) * KP + j] = __float2bfloat16(ld.y);
      sW[(m4 + 2) * KP + j] = __float2bfloat16(ld.z);
      sW[(m4 + 3) * KP + j] = __float2bfloat16(ld.w);
    }
  }
  __syncthreads();

  const int wave = t >> 6, lane = t & 63, l16 = lane & 15, quad = lane >> 4;
  f32x4 accU[6], accV[6];
  #pragma unroll
  for (int n = 0; n < 6; ++n) { accU[n] = (f32x4){0,0,0,0}; accV[n] = (f32x4){0,0,0,0}; }

  #pragma unroll
  for (int s = 0; s < 3; ++s) {
    const int kof = s * 32 + quad * 8;
    bf16x8 au = FRAG(sA, KP, wave * 16 + l16, kof);
    bf16x8 av = FRAG(sA, KP, 64 + wave * 16 + l16, kof);
    bf16x8 bw[6];
    #pragma unroll
    for (int n = 0; n < 6; ++n) bw[n] = FRAG(sW, KP, n * 16 + l16, kof);
    #pragma unroll
    for (int n = 0; n < 6; ++n) {
      accU[n] = __builtin_amdgcn_mfma_f32_16x16x32_bf16(au, bw[n], accU[n], 0, 0, 0);
      accV[n] = __builtin_amdgcn_mfma_f32_16x16x32_bf16(av, bw[n], accV[n], 0, 0, 0);
    }
  }
  __syncthreads();  // all layer-1 reads of sA/sW complete

  {
    const float* wsrc = w2 + nb * BS_ * BS_;
    #pragma unroll
    for (int it = 0; it < 9; ++it) {
      int e4 = t + 256 * it;
      int j = e4 / 24, m4 = (e4 - j * 24) * 4;
      float4 ld = *(const float4*)(wsrc + j * 96 + m4);
      sW[(m4 + 0) * KP + j] = __float2bfloat16(ld.x);
      sW[(m4 + 1) * KP + j] = __float2bfloat16(ld.y);
      sW[(m4 + 2) * KP + j] = __float2bfloat16(ld.z);
      sW[(m4 + 3) * KP + j] = __float2bfloat16(ld.w);
    }
  }
  #pragma unroll
  for (int n = 0; n < 6; ++n) {
    const float bias = b1[cbase + n * 16 + l16];
    #pragma unroll
    for (int r = 0; r < 4; ++r) {
      float o1r = fmaxf(accU[n][r] + bias, 0.0f);
      float o1i = fmaxf(accV[n][r] + bias, 0.0f);
      const int row = wave * 16 + quad * 4 + r;
      sA[row * KP + n * 16 + l16]        = __float2bfloat16(o1r - o1i);  // p
      sA[(64 + row) * KP + n * 16 + l16] = __float2bfloat16(o1r + o1i);  // q
    }
  }
  __syncthreads();

  #pragma unroll
  for (int n = 0; n < 6; ++n) { accU[n] = (f32x4){0,0,0,0}; accV[n] = (f32x4){0,0,0,0}; }
  #pragma unroll
  for (int s = 0; s < 3; ++s) {
    const int kof = s * 32 + quad * 8;
    bf16x8 ap = FRAG(sA, KP, wave * 16 + l16, kof);
    bf16x8 aq = FRAG(sA, KP, 64 + wave * 16 + l16, kof);
    bf16x8 bw[6];
    #pragma unroll
    for (int n = 0; n < 6; ++n) bw[n] = FRAG(sW, KP, n * 16 + l16, kof);
    #pragma unroll
    for (int n = 0; n < 6; ++n) {
      accU[n] = __builtin_amdgcn_mfma_f32_16x16x32_bf16(ap, bw[n], accU[n], 0, 0, 0);
      accV[n] = __builtin_amdgcn_mfma_f32_16x16x32_bf16(aq, bw[n], accV[n], 0, 0, 0);
    }
  }

  #pragma unroll
  for (int n = 0; n < 6; ++n) {
    const float bias = b2[cbase + n * 16 + l16];
    #pragma unroll
    for (int r = 0; r < 4; ++r) {
      const int row = wave * 16 + quad * 4 + r;
      float o2r = accU[n][r] + bias;
      float o2i = accV[n][r] + bias;
      o2r = (o2r > LAM_) ? (o2r - LAM_) : ((o2r < -LAM_) ? (o2r + LAM_) : 0.0f);
      o2i = (o2i > LAM_) ? (o2i - LAM_) : ((o2i < -LAM_) ? (o2i + LAM_) : 0.0f);
      const size_t o = (size_t)(p0 + row) * D_ + cbase + n * 16 + l16;
      gr[o] = __float2bfloat16(o2r);
      gi[o] = __float2bfloat16(o2i);
    }
  }
}

// ---------------- weight transpose+cast: W (K x N fp32) -> Wt (N x K bf16) ----
__global__ __launch_bounds__(256) void wtrans_kernel(
    const float* __restrict__ Wm, bf16* __restrict__ Wt, int K, int N) {
  __shared__ float tile[32][33];
  const int n0 = blockIdx.x * 32;
  const int k0 = blockIdx.y * 32;
  const int tx = threadIdx.x & 31;
  const int ty = threadIdx.x >> 5;   // 0..7
  #pragma unroll
  for (int r = 0; r < 32; r += 8)
    tile[ty + r][tx] = Wm[(size_t)(k0 + ty + r) * N + n0 + tx];
  __syncthreads();
  #pragma unroll
  for (int r = 0; r < 32; r += 8)
    Wt[(size_t)(n0 + ty + r) * K + k0 + tx] = __float2bfloat16(tile[tx][ty + r]);
}

// ---------------- MFMA GEMM: out = act(A @ Bt^T + bias) [+ resid] ----------------
// 2-phase double-buffered LDS (stage next || compute cur, one barrier per tile),
// XOR-swizzled K-slots: LDS dest linear, global source column slot^=(row>>1)&3,
// read offset applies the same involution -> conflict-free ds_read_b128.
template <int MODE, typename TOUT>
__global__ __launch_bounds__(256) void mfma_gemm_kernel(
    const bf16* __restrict__ A, const bf16* __restrict__ Bt,
    const float* __restrict__ bias, const bf16* __restrict__ resid,
    TOUT* __restrict__ out, int M, int N, int K) {
  __shared__ __align__(16) bf16 As[2][128 * 32];
  __shared__ __align__(16) bf16 Bs[2][128 * 32];
  const int t = threadIdx.x;
  const int m0 = blockIdx.x * 128;
  const int n0 = blockIdx.y * 128;
  const int wave = t >> 6;
  const int lane = t & 63;
  const int wm = (wave & 1) * 64;
  const int wn = (wave >> 1) * 64;
  const int l16 = lane & 15;
  const int quad = lane >> 4;

  // staging: thread t -> linear LDS slot (row=t>>2, slot=t&3); source pre-swizzled
  const int srow = t >> 2;
  const int skof = ((t & 3) ^ ((srow >> 1) & 3)) * 8;
  const bf16* Ag0 = A + (size_t)(m0 + srow) * K + skof;
  const bf16* Ag1 = A + (size_t)(m0 + 64 + srow) * K + skof;
  const bf16* Bg0 = Bt + (size_t)(n0 + srow) * K + skof;
  const bf16* Bg1 = Bt + (size_t)(n0 + 64 + srow) * K + skof;

  // k-tile-invariant swizzled read offsets
  int aoff[4], boff[4];
  #pragma unroll
  for (int i = 0; i < 4; ++i) {
    const int ra = wm + i * 16 + l16;
    aoff[i] = ra * 32 + (quad ^ ((ra >> 1) & 3)) * 8;
    const int rb = wn + i * 16 + l16;
    boff[i] = rb * 32 + (quad ^ ((rb >> 1) & 3)) * 8;
  }

  f32x4 acc[4][4];
  #pragma unroll
  for (int i = 0; i < 4; ++i)
    #pragma unroll
    for (int j = 0; j < 4; ++j) acc[i][j] = (f32x4){0.f, 0.f, 0.f, 0.f};

#define STAGE_G(bb, ko) do { \
    GLOAD_LDS16(Ag0 + (ko), &As[bb][t * 8]); \
    GLOAD_LDS16(Ag1 + (ko), &As[bb][2048 + t * 8]); \
    GLOAD_LDS16(Bg0 + (ko), &Bs[bb][t * 8]); \
    GLOAD_LDS16(Bg1 + (ko), &Bs[bb][2048 + t * 8]); } while (0)

#define COMPUTE_T(bb) do { \
    bf16x8 af[4], bfr[4]; \
    _Pragma("unroll") \
    for (int i = 0; i < 4; ++i) af[i] = *(const bf16x8*)(As[bb] + aoff[i]); \
    _Pragma("unroll") \
    for (int j = 0; j < 4; ++j) bfr[j] = *(const bf16x8*)(Bs[bb] + boff[j]); \
    _Pragma("unroll") \
    for (int i = 0; i < 4; ++i) \
      _Pragma("unroll") \
      for (int j = 0; j < 4; ++j) \
        acc[i][j] = __builtin_amdgcn_mfma_f32_16x16x32_bf16(af[i], bfr[j], acc[i][j], 0, 0, 0); \
  } while (0)

  const int NT = K >> 5;
  STAGE_G(0, 0);
  asm volatile("s_waitcnt vmcnt(0)" ::: "memory");
  __builtin_amdgcn_s_barrier();
  asm volatile("" ::: "memory");
  int cur = 0;
  for (int tt = 0; tt + 1 < NT; ++tt) {
    STAGE_G(cur ^ 1, (tt + 1) << 5);   // loads fly under this tile's compute
    COMPUTE_T(cur);
    asm volatile("s_waitcnt vmcnt(0)" ::: "memory");
    __builtin_amdgcn_s_barrier();
    asm volatile("" ::: "memory");
    cur ^= 1;
  }
  COMPUTE_T(cur);
#undef STAGE_G
#undef COMPUTE_T

  #pragma unroll
  for (int i = 0; i < 4; ++i) {
    #pragma unroll
    for (int j = 0; j < 4; ++j) {
      const int n = n0 + wn + j * 16 + l16;
      const float bz = bias[n];
      #pragma unroll
      for (int r = 0; r < 4; ++r) {
        const int m = m0 + wm + i * 16 + quad * 4 + r;
        float v = acc[i][j][r] + bz;
        if (MODE == 0) {
          // gelu(x) ~= x * sigmoid(1.5957691*(x + 0.044715 x^3)); |err| < 4e-4
          float q = v * fmaf(0.044715f, v * v, 1.0f);
          float e = __expf(-1.5957691216f * q);
          v = v * __builtin_amdgcn_rcpf(1.0f + e);
        } else {
          v += ldf(resid + (size_t)m * N + n);
        }
        stf(out + (size_t)m * N + n, v);
      }
    }
  }
}

extern "C" void kernel_launch(void* const* d_in, const int* in_sizes, int n_in,
                              void* d_out, int out_size, void* d_ws, size_t ws_size,
                              hipStream_t stream) {
  const float* x     = (const float*)d_in[0];
  const float* w1    = (const float*)d_in[1];
  const float* b1    = (const float*)d_in[2];
  const float* w2    = (const float*)d_in[3];
  const float* b2    = (const float*)d_in[4];
  const float* ln1w  = (const float*)d_in[5];
  const float* ln1b  = (const float*)d_in[6];
  const float* ln2w  = (const float*)d_in[7];
  const float* ln2b  = (const float*)d_in[8];
  const float* mlpw1 = (const float*)d_in[9];
  const float* mlpb1 = (const float*)d_in[10];
  const float* mlpw2 = (const float*)d_in[11];
  const float* mlpb2 = (const float*)d_in[12];
  float* out = (float*)d_out;

  const size_t SPA = (size_t)B_ * H_ * W_ * D_;   // 25,165,824 elems
  const size_t FRE = (size_t)B_ * H_ * WF_ * D_;  // 12,779,520 elems
  bf16* ws   = (bf16*)d_ws;
  bf16* bufA = ws;               // xn, later xsp (residual2)
  bf16* Fr   = bufA + SPA;
  bf16* Fi   = Fr + FRE;
  bf16* Gr   = Fi + FRE;
  bf16* Gi   = Gr + FRE;
  bf16* hid  = Fr;                              // GEMM-phase overlays
  bf16* xn2c = Gr;
  bf16* w1t  = xn2c + (size_t)CHTOK_ * D_;
  bf16* w2t  = w1t + (size_t)D_ * HID_;

  // twiddle LUTs live in d_out (dead until the final GEMM phase writes it)
  bf16* lut = (bf16*)d_out;

  const int nspec = B_ * H_ * WF_;  // 16640

  hipLaunchKernelGGL(lut_init, dim3(LUT_TOTAL / 256), dim3(256), 0, stream, lut);
  hipLaunchKernelGGL((ln_kernel<float>), dim3(NTOK_), dim3(256), 0, stream, x, ln1w, ln1b, bufA);
  hipLaunchKernelGGL(s1_rfftw, dim3(B_ * H_, D_ / 64), dim3(256), 0, stream,
                     bufA, lut + LUT_S1_OFF, Fr, Fi);
  hipLaunchKernelGGL(s2_ffth, dim3(B_ * WF_, D_ / 64), dim3(256), 0, stream,
                     Fr, Fi, Gr, Gi, lut + LUT_S2M_OFF);
  hipLaunchKernelGGL(blockmlp_mfma, dim3(nspec / 64, NB_), dim3(256), 0, stream,
                     Gr, Gi, w1, b1, w2, b2);
  hipLaunchKernelGGL(s2_ffth, dim3(B_ * WF_, D_ / 64), dim3(256), 0, stream,
                     Gr, Gi, Fr, Fi, lut + LUT_S2P_OFF);
  hipLaunchKernelGGL(s3_irfftw, dim3(B_ * H_, D_ / 64), dim3(256), 0, stream,
                     Fr, Fi, lut + LUT_S3_OFF, x, bufA);

  hipLaunchKernelGGL(wtrans_kernel, dim3(HID_ / 32, D_ / 32), dim3(256), 0, stream,
                     mlpw1, w1t, D_, HID_);
  hipLaunchKernelGGL(wtrans_kernel, dim3(D_ / 32, HID_ / 32), dim3(256), 0, stream,
                     mlpw2, w2t, HID_, D_);

  for (int c = 0; c < B_; ++c) {
    const bf16* rs = bufA + (size_t)c * CHTOK_ * D_;
    float* oc = out + (size_t)c * CHTOK_ * D_;
    hipLaunchKernelGGL((ln_kernel<bf16>), dim3(CHTOK_), dim3(256), 0, stream,
                       rs, ln2w, ln2b, xn2c);
    hipLaunchKernelGGL((mfma_gemm_kernel<0, bf16>), dim3(CHTOK_ / 128, HID_ / 128), dim3(256), 0,
                       stream, xn2c, w1t, mlpb1, (const bf16*)nullptr, hid, CHTOK_, HID_, D_);
    hipLaunchKernelGGL((mfma_gemm_kernel<1, float>), dim3(CHTOK_ / 128, D_ / 128), dim3(256), 0,
                       stream, hid, w2t, mlpb2, rs, oc, CHTOK_, D_, HID_);
  }
}

// Round 5
// 924.196 us; speedup vs baseline: 1.5775x; 1.0228x over previous
//
#include <hip/hip_runtime.h>
#include <hip/hip_bf16.h>
#include <math.h>

#define B_    4
#define H_    64
#define W_    128
#define WF_   65
#define D_    768
#define NB_   8
#define BS_   96
#define HID_  3072
#define NTOK_ 32768
#define CHTOK_ 8192
#define LAM_  0.01f

typedef __hip_bfloat16 bf16;
typedef __attribute__((ext_vector_type(8))) short bf16x8;
typedef __attribute__((ext_vector_type(4))) float f32x4;
typedef unsigned int u32;

__device__ __forceinline__ float ldf(const float* p) { return *p; }
__device__ __forceinline__ float ldf(const bf16* p)  { return __bfloat162float(*p); }
__device__ __forceinline__ void stf(float* p, float v) { *p = v; }
__device__ __forceinline__ void stf(bf16* p, float v)  { *p = __float2bfloat16(v); }

#define GLOAD_LDS16(g, l) \
  __builtin_amdgcn_global_load_lds((const __attribute__((address_space(1))) u32*)(g), \
                                   (__attribute__((address_space(3))) u32*)(l), 16, 0, 0)

// fragment read from LDS row-major [row][Kpad]
#define FRAG(arr, KP, row, kof) (*(const bf16x8*)((arr) + (size_t)(row) * (KP) + (kof)))

// ---- LUT global layout (bf16 elems), banks padded to 4096B multiples ----
#define LUT_S1_OFF  0
#define LUT_S2M_OFF 22528
#define LUT_S2P_OFF 36864
#define LUT_S3_OFF  51200
#define LUT_TOTAL   77824

__global__ __launch_bounds__(256) void lut_init(bf16* __restrict__ lut) {
  const int idx = blockIdx.x * 256 + threadIdx.x;  // grid 304*256 == 77824 exact
  const float s1 = 0.011048543456039806f;          // 1/sqrt(8192)
  float val = 0.f;
  if (idx < 22528) {                               // s1: C1 then C2
    int a = idx;
    if (a < 21760) {
      bool isC2 = a >= 10880; if (isC2) a -= 10880;
      int f = a / 136, w = a - f * 136;
      if (w < 128) {
        int p = (f * w) & 127;
        float ang = p * 0.04908738521234052f;      // 2*pi/128
        val = isC2 ? -s1 * sinf(ang) : s1 * cosf(ang);
      }
    }
  } else if (idx < 51200) {                        // s2: bank m then bank p
    int a = idx - 22528;
    float esign = -1.f;
    if (a >= 14336) { a -= 14336; esign = 1.f; }
    if (a < 13824) {
      int which = a / 4608; a -= which * 4608;
      int k = a / 72, h = a - k * 72;
      if (h < 64) {
        int p = (k * h) & 63;
        float ang = p * 0.09817477042468103f;      // 2*pi/64
        float c = cosf(ang), s = esign * sinf(ang);
        val = (which == 0) ? c : ((which == 1) ? s : -s);
      }
    }
  } else {                                         // s3: Cr then Ci
    int a = idx - 51200;
    bool isCi = a >= 13312; if (isCi) a -= 13312;
    int w = a / 104, f = a - w * 104;
    if (f < WF_) {
      int p = (f * w) & 127;
      float ang = p * 0.04908738521234052f;
      float al = (f == 0 || f == 64) ? 1.0f : 2.0f;
      val = isCi ? -s1 * al * sinf(ang) : s1 * al * cosf(ang);
    }
  }
  lut[idx] = __float2bfloat16(val);
}

// ---------------- LayerNorm (one block per token, 768 = 3*256) ----------------
template <typename TIN>
__global__ __launch_bounds__(256) void ln_kernel(
    const TIN* __restrict__ x, const float* __restrict__ g,
    const float* __restrict__ bta, bf16* __restrict__ out) {
  __shared__ float sred[8];
  const size_t base = (size_t)blockIdx.x * D_;
  const int t = threadIdx.x;
  float v0 = ldf(x + base + t);
  float v1 = ldf(x + base + t + 256);
  float v2 = ldf(x + base + t + 512);
  float s = v0 + v1 + v2;
  #pragma unroll
  for (int o = 32; o; o >>= 1) s += __shfl_down(s, o, 64);
  int lane = t & 63, wid = t >> 6;
  if (lane == 0) sred[wid] = s;
  __syncthreads();
  if (t == 0) sred[0] = sred[0] + sred[1] + sred[2] + sred[3];
  __syncthreads();
  float mean = sred[0] * (1.0f / D_);
  float d0 = v0 - mean, d1 = v1 - mean, d2 = v2 - mean;
  float q = d0 * d0 + d1 * d1 + d2 * d2;
  #pragma unroll
  for (int o = 32; o; o >>= 1) q += __shfl_down(q, o, 64);
  if (lane == 0) sred[4 + wid] = q;
  __syncthreads();
  if (t == 0) sred[4] = sred[4] + sred[5] + sred[6] + sred[7];
  __syncthreads();
  float rstd = rsqrtf(sred[4] * (1.0f / D_) + 1e-5f);
  stf(out + base + t,       d0 * rstd * g[t]       + bta[t]);
  stf(out + base + t + 256, d1 * rstd * g[t + 256] + bta[t + 256]);
  stf(out + base + t + 512, d2 * rstd * g[t + 512] + bta[t + 512]);
}

// ============ S1: rfft along W as MFMA GEMM. block=(bh, ctile64) ============
__global__ __launch_bounds__(256) void s1_rfftw(
    const bf16* __restrict__ xn, const bf16* __restrict__ lut,
    bf16* __restrict__ fr, bf16* __restrict__ fi) {
  const int KP = 136;  // 128 + pad (272 B rows, 16B aligned)
  __shared__ __align__(16) bf16 sC[22528];       // C1 @0, C2 @10880 (+pad)
  __shared__ __align__(16) bf16 sXt[64 * 136];
  const int t = threadIdx.x;
  const int bh = blockIdx.x;
  const int c0 = blockIdx.y * 64;

  #pragma unroll
  for (int it = 0; it < 11; ++it)
    GLOAD_LDS16((const char*)lut + t * 16 + it * 4096, (char*)sC + t * 16 + it * 4096);

  {
    const int cv = (t & 7) * 8;
    #pragma unroll
    for (int rep = 0; rep < 4; ++rep) {
      int w = (t >> 3) + 32 * rep;
      bf16x8 v = *(const bf16x8*)(xn + ((size_t)bh * W_ + w) * D_ + c0 + cv);
      #pragma unroll
      for (int i = 0; i < 8; ++i) sXt[(cv + i) * KP + w] = ((const bf16*)&v)[i];
    }
  }
  __syncthreads();
  const bf16* sC1 = sC;
  const bf16* sC2 = sC + 10880;

  const int wave = t >> 6, lane = t & 63, l16 = lane & 15, quad = lane >> 4;
  const int ni = (wave == 0) ? 2 : 1;
  int itile[2] = {wave, 4};
  f32x4 accR[2][4], accI[2][4];
  #pragma unroll
  for (int ii = 0; ii < 2; ++ii)
    #pragma unroll
    for (int j = 0; j < 4; ++j) { accR[ii][j] = (f32x4){0,0,0,0}; accI[ii][j] = (f32x4){0,0,0,0}; }

  for (int s = 0; s < 4; ++s) {
    const int kof = s * 32 + quad * 8;
    bf16x8 bfrag[4];
    #pragma unroll
    for (int j = 0; j < 4; ++j) bfrag[j] = FRAG(sXt, KP, j * 16 + l16, kof);
    for (int ii = 0; ii < ni; ++ii) {
      const int arow = 16 * itile[ii] + l16;
      bf16x8 a1 = FRAG(sC1, KP, arow, kof);
      bf16x8 a2 = FRAG(sC2, KP, arow, kof);
      #pragma unroll
      for (int j = 0; j < 4; ++j) {
        accR[ii][j] = __builtin_amdgcn_mfma_f32_16x16x32_bf16(a1, bfrag[j], accR[ii][j], 0, 0, 0);
        accI[ii][j] = __builtin_amdgcn_mfma_f32_16x16x32_bf16(a2, bfrag[j], accI[ii][j], 0, 0, 0);
      }
    }
  }
  for (int ii = 0; ii < ni; ++ii) {
    #pragma unroll
    for (int r = 0; r < 4; ++r) {
      const int f = 16 * itile[ii] + quad * 4 + r;
      if (f >= WF_) continue;
      const size_t ob = ((size_t)bh * WF_ + f) * D_ + c0;
      #pragma unroll
      for (int j = 0; j < 4; ++j) {
        fr[ob + j * 16 + l16] = __float2bfloat16(accR[ii][j][r]);
        fi[ob + j * 16 + l16] = __float2bfloat16(accI[ii][j][r]);
      }
    }
  }
}

// ============ S2: FFT along H as MFMA GEMM. block=(b*WF+f, ctile64) ============
__global__ __launch_bounds__(256) void s2_ffth(
    const bf16* __restrict__ inr, const bf16* __restrict__ ini,
    bf16* __restrict__ outr, bf16* __restrict__ outi, const bf16* __restrict__ lut) {
  const int KP = 72;  // 64 + pad (144 B rows)
  __shared__ __align__(16) bf16 sT[14336];       // Tr @0, Ti @4608, Tn @9216 (+pad)
  __shared__ __align__(16) bf16 sFtr[64 * 72];
  __shared__ __align__(16) bf16 sFti[64 * 72];
  const int t = threadIdx.x;
  const int b = blockIdx.x / WF_;
  const int f = blockIdx.x % WF_;
  const int c0 = blockIdx.y * 64;

  #pragma unroll
  for (int it = 0; it < 7; ++it)
    GLOAD_LDS16((const char*)lut + t * 16 + it * 4096, (char*)sT + t * 16 + it * 4096);

  {
    const int cv = (t & 7) * 8;
    #pragma unroll
    for (int rep = 0; rep < 2; ++rep) {
      int h = (t >> 3) + 32 * rep;
      size_t g = ((size_t)(b * H_ + h) * WF_ + f) * D_ + c0 + cv;
      bf16x8 vr = *(const bf16x8*)(inr + g);
      bf16x8 vi = *(const bf16x8*)(ini + g);
      #pragma unroll
      for (int i = 0; i < 8; ++i) {
        sFtr[(cv + i) * KP + h] = ((const bf16*)&vr)[i];
        sFti[(cv + i) * KP + h] = ((const bf16*)&vi)[i];
      }
    }
  }
  __syncthreads();
  const bf16* sTr = sT;
  const bf16* sTi = sT + 4608;
  const bf16* sTn = sT + 9216;

  const int wave = t >> 6, lane = t & 63, l16 = lane & 15, quad = lane >> 4;
  f32x4 accR[4], accI[4];
  #pragma unroll
  for (int j = 0; j < 4; ++j) { accR[j] = (f32x4){0,0,0,0}; accI[j] = (f32x4){0,0,0,0}; }

  #pragma unroll
  for (int s = 0; s < 2; ++s) {
    const int kof = s * 32 + quad * 8;
    const int arow = 16 * wave + l16;
    bf16x8 ar = FRAG(sTr, KP, arow, kof);
    bf16x8 ai = FRAG(sTi, KP, arow, kof);
    bf16x8 an = FRAG(sTn, KP, arow, kof);
    #pragma unroll
    for (int j = 0; j < 4; ++j) {
      const int brow = j * 16 + l16;
      bf16x8 br = FRAG(sFtr, KP, brow, kof);
      bf16x8 bi = FRAG(sFti, KP, brow, kof);
      accR[j] = __builtin_amdgcn_mfma_f32_16x16x32_bf16(ar, br, accR[j], 0, 0, 0);
      accR[j] = __builtin_amdgcn_mfma_f32_16x16x32_bf16(an, bi, accR[j], 0, 0, 0);
      accI[j] = __builtin_amdgcn_mfma_f32_16x16x32_bf16(ai, br, accI[j], 0, 0, 0);
      accI[j] = __builtin_amdgcn_mfma_f32_16x16x32_bf16(ar, bi, accI[j], 0, 0, 0);
    }
  }
  #pragma unroll
  for (int r = 0; r < 4; ++r) {
    const int k = 16 * wave + quad * 4 + r;
    const size_t ob = ((size_t)(b * H_ + k) * WF_ + f) * D_ + c0;
    #pragma unroll
    for (int j = 0; j < 4; ++j) {
      outr[ob + j * 16 + l16] = __float2bfloat16(accR[j][r]);
      outi[ob + j * 16 + l16] = __float2bfloat16(accI[j][r]);
    }
  }
}

// ============ S3: irfft along W + residual, MFMA. block=(bh, ctile64) ============
__global__ __launch_bounds__(256) void s3_irfftw(
    const bf16* __restrict__ fr, const bf16* __restrict__ fi,
    const bf16* __restrict__ lut, const float* __restrict__ x0, bf16* __restrict__ xsp) {
  const int KP = 104;  // 96 + pad (208 B rows)
  __shared__ __align__(16) bf16 sC[26624];       // Cr @0, Ci @13312
  __shared__ __align__(16) bf16 sGtr[64 * 104];
  __shared__ __align__(16) bf16 sGti[64 * 104];
  const int t = threadIdx.x;
  const int bh = blockIdx.x;
  const int c0 = blockIdx.y * 64;

  #pragma unroll
  for (int it = 0; it < 13; ++it)
    GLOAD_LDS16((const char*)lut + t * 16 + it * 4096, (char*)sC + t * 16 + it * 4096);

  {
    const int cv = (t & 7) * 8;
    #pragma unroll
    for (int rep = 0; rep < 2; ++rep) {
      int f = (t >> 3) + 32 * rep;
      size_t g = ((size_t)bh * WF_ + f) * D_ + c0 + cv;
      bf16x8 vr = *(const bf16x8*)(fr + g);
      bf16x8 vi = *(const bf16x8*)(fi + g);
      #pragma unroll
      for (int i = 0; i < 8; ++i) {
        sGtr[(cv + i) * KP + f] = ((const bf16*)&vr)[i];
        sGti[(cv + i) * KP + f] = ((const bf16*)&vi)[i];
      }
    }
    if (t < 8) {  // f = 64 row
      size_t g = ((size_t)bh * WF_ + 64) * D_ + c0 + cv;
      bf16x8 vr = *(const bf16x8*)(fr + g);
      bf16x8 vi = *(const bf16x8*)(fi + g);
      #pragma unroll
      for (int i = 0; i < 8; ++i) {
        sGtr[(cv + i) * KP + 64] = ((const bf16*)&vr)[i];
        sGti[(cv + i) * KP + 64] = ((const bf16*)&vi)[i];
      }
    }
    const bf16 z = __float2bfloat16(0.f);
    for (int e = t; e < 64 * 31; e += 256) {
      int c = e / 31, f = 65 + (e - (e / 31) * 31);
      sGtr[c * KP + f] = z;
      sGti[c * KP + f] = z;
    }
  }
  __syncthreads();
  const bf16* sCr = sC;
  const bf16* sCi = sC + 13312;

  const int wave = t >> 6, lane = t & 63, l16 = lane & 15, quad = lane >> 4;
  f32x4 acc[2][4];
  #pragma unroll
  for (int ii = 0; ii < 2; ++ii)
    #pragma unroll
    for (int j = 0; j < 4; ++j) acc[ii][j] = (f32x4){0,0,0,0};

  #pragma unroll
  for (int s = 0; s < 3; ++s) {
    const int kof = s * 32 + quad * 8;
    bf16x8 br[4], bi[4];
    #pragma unroll
    for (int j = 0; j < 4; ++j) {
      br[j] = FRAG(sGtr, KP, j * 16 + l16, kof);
      bi[j] = FRAG(sGti, KP, j * 16 + l16, kof);
    }
    #pragma unroll
    for (int ii = 0; ii < 2; ++ii) {
      const int arow = 16 * (wave + 4 * ii) + l16;
      bf16x8 a1 = FRAG(sCr, KP, arow, kof);
      bf16x8 a2 = FRAG(sCi, KP, arow, kof);
      #pragma unroll
      for (int j = 0; j < 4; ++j) {
        acc[ii][j] = __builtin_amdgcn_mfma_f32_16x16x32_bf16(a1, br[j], acc[ii][j], 0, 0, 0);
        acc[ii][j] = __builtin_amdgcn_mfma_f32_16x16x32_bf16(a2, bi[j], acc[ii][j], 0, 0, 0);
      }
    }
  }
  #pragma unroll
  for (int ii = 0; ii < 2; ++ii) {
    #pragma unroll
    for (int r = 0; r < 4; ++r) {
      const int w = 16 * (wave + 4 * ii) + quad * 4 + r;
      const size_t ob = ((size_t)bh * W_ + w) * D_ + c0;
      #pragma unroll
      for (int j = 0; j < 4; ++j) {
        const size_t o = ob + j * 16 + l16;
        xsp[o] = __float2bfloat16(acc[ii][j][r] + x0[o]);
      }
    }
  }
}

// ============ block-diagonal complex MLP as MFMA, in place ============
__global__ __launch_bounds__(256) void blockmlp_mfma(
    bf16* __restrict__ gr, bf16* __restrict__ gi,
    const float* __restrict__ w1, const float* __restrict__ b1,
    const float* __restrict__ w2, const float* __restrict__ b2) {
  const int KP = 104;  // 96 + pad (208 B rows: 13x16B slots -> conflict-free b128)
  __shared__ __align__(16) bf16 sA[128 * 104];
  __shared__ __align__(16) bf16 sW[96 * 104];
  const int t = threadIdx.x;
  const int p0 = blockIdx.x * 64;
  const int nb = blockIdx.y;
  const int cbase = nb * BS_;

  #pragma unroll
  for (int it = 0; it < 3; ++it) {
    int task = t + 256 * it;          // 0..767
    int r = task / 12, jv = task - r * 12;
    size_t g = (size_t)(p0 + r) * D_ + cbase + jv * 8;
    bf16x8 vr = *(const bf16x8*)(gr + g);
    bf16x8 vi = *(const bf16x8*)(gi + g);
    bf16x8 u8, v8;
    #pragma unroll
    for (int i = 0; i < 8; ++i) {
      float xr = __bfloat162float(((const bf16*)&vr)[i]);
      float xi = __bfloat162float(((const bf16*)&vi)[i]);
      ((bf16*)&u8)[i] = __float2bfloat16(xr - xi);
      ((bf16*)&v8)[i] = __float2bfloat16(xr + xi);
    }
    *(bf16x8*)(sA + r * KP + jv * 8) = u8;
    *(bf16x8*)(sA + (64 + r) * KP + jv * 8) = v8;
  }
  {
    const float* wsrc = w1 + nb * BS_ * BS_;
    #pragma unroll
    for (int it = 0; it < 9; ++it) {
      int e4 = t + 256 * it;          // 0..2303 tasks of 4 elems
      int j = e4 / 24, m4 = (e4 - j * 24) * 4;
      float4 ld = *(const float4*)(wsrc + j * 96 + m4);
      sW[(m4 + 0) * KP + j] = __float2bfloat16(ld.x);
      sW[(m4 + 1) * KP + j] = __float2bfloat16(ld.y);
      sW[(m4 + 2) * KP + j] = __float2bfloat16(ld.z);
      sW[(m4 + 3) * KP + j] = __float2bfloat16(ld.w);
    }
  }
  __syncthreads();

  const int wave = t >> 6, lane = t & 63, l16 = lane & 15, quad = lane >> 4;
  f32x4 accU[6], accV[6];
  #pragma unroll
  for (int n = 0; n < 6; ++n) { accU[n] = (f32x4){0,0,0,0}; accV[n] = (f32x4){0,0,0,0}; }

  #pragma unroll
  for (int s = 0; s < 3; ++s) {
    const int kof = s * 32 + quad * 8;
    bf16x8 au = FRAG(sA, KP, wave * 16 + l16, kof);
    bf16x8 av = FRAG(sA, KP, 64 + wave * 16 + l16, kof);
    bf16x8 bw[6];
    #pragma unroll
    for (int n = 0; n < 6; ++n) bw[n] = FRAG(sW, KP, n * 16 + l16, kof);
    #pragma unroll
    for (int n = 0; n < 6; ++n) {
      accU[n] = __builtin_amdgcn_mfma_f32_16x16x32_bf16(au, bw[n], accU[n], 0, 0, 0);
      accV[n] = __builtin_amdgcn_mfma_f32_16x16x32_bf16(av, bw[n], accV[n], 0, 0, 0);
    }
  }
  __syncthreads();  // all layer-1 reads of sA/sW complete

  {
    const float* wsrc = w2 + nb * BS_ * BS_;
    #pragma unroll
    for (int it = 0; it < 9; ++it) {
      int e4 = t + 256 * it;
      int j = e4 / 24, m4 = (e4 - j * 24) * 4;
      float4 ld = *(const float4*)(wsrc + j * 96 + m4);
      sW[(m4 + 0) * KP + j] = __float2bfloat16(ld.x);
      sW[(m4 + 1) * KP + j] = __float2bfloat16(ld.y);
      sW[(m4 + 2) * KP + j] = __float2bfloat16(ld.z);
      sW[(m4 + 3) * KP + j] = __float2bfloat16(ld.w);
    }
  }
  #pragma unroll
  for (int n = 0; n < 6; ++n) {
    const float bias = b1[cbase + n * 16 + l16];
    #pragma unroll
    for (int r = 0; r < 4; ++r) {
      float o1r = fmaxf(accU[n][r] + bias, 0.0f);
      float o1i = fmaxf(accV[n][r] + bias, 0.0f);
      const int row = wave * 16 + quad * 4 + r;
      sA[row * KP + n * 16 + l16]        = __float2bfloat16(o1r - o1i);  // p
      sA[(64 + row) * KP + n * 16 + l16] = __float2bfloat16(o1r + o1i);  // q
    }
  }
  __syncthreads();

  #pragma unroll
  for (int n = 0; n < 6; ++n) { accU[n] = (f32x4){0,0,0,0}; accV[n] = (f32x4){0,0,0,0}; }
  #pragma unroll
  for (int s = 0; s < 3; ++s) {
    const int kof = s * 32 + quad * 8;
    bf16x8 ap = FRAG(sA, KP, wave * 16 + l16, kof);
    bf16x8 aq = FRAG(sA, KP, 64 + wave * 16 + l16, kof);
    bf16x8 bw[6];
    #pragma unroll
    for (int n = 0; n < 6; ++n) bw[n] = FRAG(sW, KP, n * 16 + l16, kof);
    #pragma unroll
    for (int n = 0; n < 6; ++n) {
      accU[n] = __builtin_amdgcn_mfma_f32_16x16x32_bf16(ap, bw[n], accU[n], 0, 0, 0);
      accV[n] = __builtin_amdgcn_mfma_f32_16x16x32_bf16(aq, bw[n], accV[n], 0, 0, 0);
    }
  }

  #pragma unroll
  for (int n = 0; n < 6; ++n) {
    const float bias = b2[cbase + n * 16 + l16];
    #pragma unroll
    for (int r = 0; r < 4; ++r) {
      const int row = wave * 16 + quad * 4 + r;
      float o2r = accU[n][r] + bias;
      float o2i = accV[n][r] + bias;
      o2r = (o2r > LAM_) ? (o2r - LAM_) : ((o2r < -LAM_) ? (o2r + LAM_) : 0.0f);
      o2i = (o2i > LAM_) ? (o2i - LAM_) : ((o2i < -LAM_) ? (o2i + LAM_) : 0.0f);
      const size_t o = (size_t)(p0 + row) * D_ + cbase + n * 16 + l16;
      gr[o] = __float2bfloat16(o2r);
      gi[o] = __float2bfloat16(o2i);
    }
  }
}

// ---------------- weight transpose+cast: W (K x N fp32) -> Wt (N x K bf16) ----
__global__ __launch_bounds__(256) void wtrans_kernel(
    const float* __restrict__ Wm, bf16* __restrict__ Wt, int K, int N) {
  __shared__ float tile[32][33];
  const int n0 = blockIdx.x * 32;
  const int k0 = blockIdx.y * 32;
  const int tx = threadIdx.x & 31;
  const int ty = threadIdx.x >> 5;   // 0..7
  #pragma unroll
  for (int r = 0; r < 32; r += 8)
    tile[ty + r][tx] = Wm[(size_t)(k0 + ty + r) * N + n0 + tx];
  __syncthreads();
  #pragma unroll
  for (int r = 0; r < 32; r += 8)
    Wt[(size_t)(n0 + ty + r) * K + k0 + tx] = __float2bfloat16(tile[tx][ty + r]);
}

// ---------------- MFMA GEMM: out = act(A @ Bt^T + bias) [+ resid] ----------------
// 3-deep LDS rotation with COUNTED vmcnt (T4): never drain to 0 in the main loop.
// Steady state: stage tile t+2 (8 loads in flight), compute tile t, vmcnt(4)
// waits only for tile t+1 (issued one full compute earlier -> latency hidden).
// XOR-swizzled K-slots (source-side + read-side involution, LDS dest linear).
template <int MODE, typename TOUT>
__global__ __launch_bounds__(256) void mfma_gemm_kernel(
    const bf16* __restrict__ A, const bf16* __restrict__ Bt,
    const float* __restrict__ bias, const bf16* __restrict__ resid,
    TOUT* __restrict__ out, int M, int N, int K) {
  __shared__ __align__(16) bf16 As[3][128 * 32];
  __shared__ __align__(16) bf16 Bs[3][128 * 32];
  const int t = threadIdx.x;
  const int m0 = blockIdx.x * 128;
  const int n0 = blockIdx.y * 128;
  const int wave = t >> 6;
  const int lane = t & 63;
  const int wm = (wave & 1) * 64;
  const int wn = (wave >> 1) * 64;
  const int l16 = lane & 15;
  const int quad = lane >> 4;

  // staging: thread t -> linear LDS slot (row=t>>2, slot=t&3); source pre-swizzled
  const int srow = t >> 2;
  const int skof = ((t & 3) ^ ((srow >> 1) & 3)) * 8;
  const bf16* Ag0 = A + (size_t)(m0 + srow) * K + skof;
  const bf16* Ag1 = A + (size_t)(m0 + 64 + srow) * K + skof;
  const bf16* Bg0 = Bt + (size_t)(n0 + srow) * K + skof;
  const bf16* Bg1 = Bt + (size_t)(n0 + 64 + srow) * K + skof;

  // k-tile-invariant swizzled read offsets
  int aoff[4], boff[4];
  #pragma unroll
  for (int i = 0; i < 4; ++i) {
    const int ra = wm + i * 16 + l16;
    aoff[i] = ra * 32 + (quad ^ ((ra >> 1) & 3)) * 8;
    const int rb = wn + i * 16 + l16;
    boff[i] = rb * 32 + (quad ^ ((rb >> 1) & 3)) * 8;
  }

  f32x4 acc[4][4];
  #pragma unroll
  for (int i = 0; i < 4; ++i)
    #pragma unroll
    for (int j = 0; j < 4; ++j) acc[i][j] = (f32x4){0.f, 0.f, 0.f, 0.f};

#define STAGE_G(bb, ko) do { \
    GLOAD_LDS16(Ag0 + (ko), &As[bb][t * 8]); \
    GLOAD_LDS16(Ag1 + (ko), &As[bb][2048 + t * 8]); \
    GLOAD_LDS16(Bg0 + (ko), &Bs[bb][t * 8]); \
    GLOAD_LDS16(Bg1 + (ko), &Bs[bb][2048 + t * 8]); } while (0)

#define COMPUTE_T(bb) do { \
    bf16x8 af[4], bfr[4]; \
    _Pragma("unroll") \
    for (int i = 0; i < 4; ++i) af[i] = *(const bf16x8*)(As[bb] + aoff[i]); \
    _Pragma("unroll") \
    for (int j = 0; j < 4; ++j) bfr[j] = *(const bf16x8*)(Bs[bb] + boff[j]); \
    __builtin_amdgcn_s_setprio(1); \
    _Pragma("unroll") \
    for (int i = 0; i < 4; ++i) \
      _Pragma("unroll") \
      for (int j = 0; j < 4; ++j) \
        acc[i][j] = __builtin_amdgcn_mfma_f32_16x16x32_bf16(af[i], bfr[j], acc[i][j], 0, 0, 0); \
    __builtin_amdgcn_s_setprio(0); \
  } while (0)

#define WAITBAR(n) do { \
    asm volatile("s_waitcnt vmcnt(" #n ")" ::: "memory"); \
    __builtin_amdgcn_s_barrier(); \
    asm volatile("" ::: "memory"); } while (0)

  const int NT = K >> 5;   // >= 3 for all call sites (24 / 96)
  STAGE_G(0, 0);
  STAGE_G(1, 32);
  WAITBAR(4);              // tile 0 landed (own loads); barrier covers peers
  int bcur = 0, bnxt = 1, bstg = 2;
  for (int tt = 0; tt < NT - 2; ++tt) {
    STAGE_G(bstg, (tt + 2) << 5);   // back to 8 in flight
    COMPUTE_T(bcur);
    WAITBAR(4);                     // tile tt+1 landed; tt+2 still flying
    int tmp = bcur; bcur = bnxt; bnxt = bstg; bstg = tmp;
  }
  COMPUTE_T(bcur);
  WAITBAR(0);                       // drain last tile
  COMPUTE_T(bnxt);
#undef STAGE_G
#undef COMPUTE_T
#undef WAITBAR

  #pragma unroll
  for (int i = 0; i < 4; ++i) {
    #pragma unroll
    for (int j = 0; j < 4; ++j) {
      const int n = n0 + wn + j * 16 + l16;
      const float bz = bias[n];
      #pragma unroll
      for (int r = 0; r < 4; ++r) {
        const int m = m0 + wm + i * 16 + quad * 4 + r;
        float v = acc[i][j][r] + bz;
        if (MODE == 0) {
          // gelu(x) ~= x * sigmoid(1.5957691*(x + 0.044715 x^3)); |err| < 4e-4
          float q = v * fmaf(0.044715f, v * v, 1.0f);
          float e = __expf(-1.5957691216f * q);
          v = v * __builtin_amdgcn_rcpf(1.0f + e);
        } else {
          v += ldf(resid + (size_t)m * N + n);
        }
        stf(out + (size_t)m * N + n, v);
      }
    }
  }
}

extern "C" void kernel_launch(void* const* d_in, const int* in_sizes, int n_in,
                              void* d_out, int out_size, void* d_ws, size_t ws_size,
                              hipStream_t stream) {
  const float* x     = (const float*)d_in[0];
  const float* w1    = (const float*)d_in[1];
  const float* b1    = (const float*)d_in[2];
  const float* w2    = (const float*)d_in[3];
  const float* b2    = (const float*)d_in[4];
  const float* ln1w  = (const float*)d_in[5];
  const float* ln1b  = (const float*)d_in[6];
  const float* ln2w  = (const float*)d_in[7];
  const float* ln2b  = (const float*)d_in[8];
  const float* mlpw1 = (const float*)d_in[9];
  const float* mlpb1 = (const float*)d_in[10];
  const float* mlpw2 = (const float*)d_in[11];
  const float* mlpb2 = (const float*)d_in[12];
  float* out = (float*)d_out;

  const size_t SPA = (size_t)B_ * H_ * W_ * D_;   // 25,165,824 elems
  const size_t FRE = (size_t)B_ * H_ * WF_ * D_;  // 12,779,520 elems
  bf16* ws   = (bf16*)d_ws;
  bf16* bufA = ws;               // xn, later xsp (residual2)
  bf16* Fr   = bufA + SPA;
  bf16* Fi   = Fr + FRE;
  bf16* Gr   = Fi + FRE;
  bf16* Gi   = Gr + FRE;
  bf16* hid  = Fr;                              // GEMM-phase overlays
  bf16* xn2c = Gr;
  bf16* w1t  = xn2c + (size_t)CHTOK_ * D_;
  bf16* w2t  = w1t + (size_t)D_ * HID_;

  // twiddle LUTs live in d_out (dead until the final GEMM phase writes it)
  bf16* lut = (bf16*)d_out;

  const int nspec = B_ * H_ * WF_;  // 16640

  hipLaunchKernelGGL(lut_init, dim3(LUT_TOTAL / 256), dim3(256), 0, stream, lut);
  hipLaunchKernelGGL((ln_kernel<float>), dim3(NTOK_), dim3(256), 0, stream, x, ln1w, ln1b, bufA);
  hipLaunchKernelGGL(s1_rfftw, dim3(B_ * H_, D_ / 64), dim3(256), 0, stream,
                     bufA, lut + LUT_S1_OFF, Fr, Fi);
  hipLaunchKernelGGL(s2_ffth, dim3(B_ * WF_, D_ / 64), dim3(256), 0, stream,
                     Fr, Fi, Gr, Gi, lut + LUT_S2M_OFF);
  hipLaunchKernelGGL(blockmlp_mfma, dim3(nspec / 64, NB_), dim3(256), 0, stream,
                     Gr, Gi, w1, b1, w2, b2);
  hipLaunchKernelGGL(s2_ffth, dim3(B_ * WF_, D_ / 64), dim3(256), 0, stream,
                     Gr, Gi, Fr, Fi, lut + LUT_S2P_OFF);
  hipLaunchKernelGGL(s3_irfftw, dim3(B_ * H_, D_ / 64), dim3(256), 0, stream,
                     Fr, Fi, lut + LUT_S3_OFF, x, bufA);

  hipLaunchKernelGGL(wtrans_kernel, dim3(HID_ / 32, D_ / 32), dim3(256), 0, stream,
                     mlpw1, w1t, D_, HID_);
  hipLaunchKernelGGL(wtrans_kernel, dim3(D_ / 32, HID_ / 32), dim3(256), 0, stream,
                     mlpw2, w2t, HID_, D_);

  for (int c = 0; c < B_; ++c) {
    const bf16* rs = bufA + (size_t)c * CHTOK_ * D_;
    float* oc = out + (size_t)c * CHTOK_ * D_;
    hipLaunchKernelGGL((ln_kernel<bf16>), dim3(CHTOK_), dim3(256), 0, stream,
                       rs, ln2w, ln2b, xn2c);
    hipLaunchKernelGGL((mfma_gemm_kernel<0, bf16>), dim3(CHTOK_ / 128, HID_ / 128), dim3(256), 0,
                       stream, xn2c, w1t, mlpb1, (const bf16*)nullptr, hid, CHTOK_, HID_, D_);
    hipLaunchKernelGGL((mfma_gemm_kernel<1, float>), dim3(CHTOK_ / 128, D_ / 128), dim3(256), 0,
                       stream, hid, w2t, mlpb2, rs, oc, CHTOK_, D_, HID_);
  }
}

// Round 6
// 837.689 us; speedup vs baseline: 1.7404x; 1.1033x over previous
//
#include <hip/hip_runtime.h>
#include <hip/hip_bf16.h>
#include <math.h>

#define B_    4
#define H_    64
#define W_    128
#define WF_   65
#define D_    768
#define NB_   8
#define BS_   96
#define HID_  3072
#define NTOK_ 32768
#define CHTOK_ 8192
#define LAM_  0.01f

typedef __hip_bfloat16 bf16;
typedef __attribute__((ext_vector_type(8))) short bf16x8;
typedef __attribute__((ext_vector_type(4))) float f32x4;
typedef unsigned int u32;

__device__ __forceinline__ float ldf(const float* p) { return *p; }
__device__ __forceinline__ float ldf(const bf16* p)  { return __bfloat162float(*p); }
__device__ __forceinline__ void stf(float* p, float v) { *p = v; }
__device__ __forceinline__ void stf(bf16* p, float v)  { *p = __float2bfloat16(v); }

#define GLOAD_LDS16(g, l) \
  __builtin_amdgcn_global_load_lds((const __attribute__((address_space(1))) u32*)(g), \
                                   (__attribute__((address_space(3))) u32*)(l), 16, 0, 0)

// fragment read from LDS row-major [row][Kpad]
#define FRAG(arr, KP, row, kof) (*(const bf16x8*)((arr) + (size_t)(row) * (KP) + (kof)))

// ---- LUT global layout (bf16 elems), banks padded to 4096B multiples ----
#define LUT_S1_OFF  0
#define LUT_S2M_OFF 22528
#define LUT_S2P_OFF 36864
#define LUT_S3_OFF  51200
#define LUT_TOTAL   77824

__global__ __launch_bounds__(256) void lut_init(bf16* __restrict__ lut) {
  const int idx = blockIdx.x * 256 + threadIdx.x;  // grid 304*256 == 77824 exact
  const float s1 = 0.011048543456039806f;          // 1/sqrt(8192)
  float val = 0.f;
  if (idx < 22528) {                               // s1: C1 then C2
    int a = idx;
    if (a < 21760) {
      bool isC2 = a >= 10880; if (isC2) a -= 10880;
      int f = a / 136, w = a - f * 136;
      if (w < 128) {
        int p = (f * w) & 127;
        float ang = p * 0.04908738521234052f;      // 2*pi/128
        val = isC2 ? -s1 * sinf(ang) : s1 * cosf(ang);
      }
    }
  } else if (idx < 51200) {                        // s2: bank m then bank p
    int a = idx - 22528;
    float esign = -1.f;
    if (a >= 14336) { a -= 14336; esign = 1.f; }
    if (a < 13824) {
      int which = a / 4608; a -= which * 4608;
      int k = a / 72, h = a - k * 72;
      if (h < 64) {
        int p = (k * h) & 63;
        float ang = p * 0.09817477042468103f;      // 2*pi/64
        float c = cosf(ang), s = esign * sinf(ang);
        val = (which == 0) ? c : ((which == 1) ? s : -s);
      }
    }
  } else {                                         // s3: Cr then Ci
    int a = idx - 51200;
    bool isCi = a >= 13312; if (isCi) a -= 13312;
    int w = a / 104, f = a - w * 104;
    if (f < WF_) {
      int p = (f * w) & 127;
      float ang = p * 0.04908738521234052f;
      float al = (f == 0 || f == 64) ? 1.0f : 2.0f;
      val = isCi ? -s1 * al * sinf(ang) : s1 * al * cosf(ang);
    }
  }
  lut[idx] = __float2bfloat16(val);
}

// ---------------- LayerNorm (one block per token, 768 = 3*256) ----------------
template <typename TIN>
__global__ __launch_bounds__(256) void ln_kernel(
    const TIN* __restrict__ x, const float* __restrict__ g,
    const float* __restrict__ bta, bf16* __restrict__ out) {
  __shared__ float sred[8];
  const size_t base = (size_t)blockIdx.x * D_;
  const int t = threadIdx.x;
  float v0 = ldf(x + base + t);
  float v1 = ldf(x + base + t + 256);
  float v2 = ldf(x + base + t + 512);
  float s = v0 + v1 + v2;
  #pragma unroll
  for (int o = 32; o; o >>= 1) s += __shfl_down(s, o, 64);
  int lane = t & 63, wid = t >> 6;
  if (lane == 0) sred[wid] = s;
  __syncthreads();
  if (t == 0) sred[0] = sred[0] + sred[1] + sred[2] + sred[3];
  __syncthreads();
  float mean = sred[0] * (1.0f / D_);
  float d0 = v0 - mean, d1 = v1 - mean, d2 = v2 - mean;
  float q = d0 * d0 + d1 * d1 + d2 * d2;
  #pragma unroll
  for (int o = 32; o; o >>= 1) q += __shfl_down(q, o, 64);
  if (lane == 0) sred[4 + wid] = q;
  __syncthreads();
  if (t == 0) sred[4] = sred[4] + sred[5] + sred[6] + sred[7];
  __syncthreads();
  float rstd = rsqrtf(sred[4] * (1.0f / D_) + 1e-5f);
  stf(out + base + t,       d0 * rstd * g[t]       + bta[t]);
  stf(out + base + t + 256, d1 * rstd * g[t + 256] + bta[t + 256]);
  stf(out + base + t + 512, d2 * rstd * g[t + 512] + bta[t + 512]);
}

// ============ S1: rfft along W as MFMA GEMM. block=(bh, ctile64) ============
__global__ __launch_bounds__(256) void s1_rfftw(
    const bf16* __restrict__ xn, const bf16* __restrict__ lut,
    bf16* __restrict__ fr, bf16* __restrict__ fi) {
  const int KP = 136;  // 128 + pad (272 B rows, 16B aligned)
  __shared__ __align__(16) bf16 sC[22528];       // C1 @0, C2 @10880 (+pad)
  __shared__ __align__(16) bf16 sXt[64 * 136];
  const int t = threadIdx.x;
  const int bh = blockIdx.x;
  const int c0 = blockIdx.y * 64;

  #pragma unroll
  for (int it = 0; it < 11; ++it)
    GLOAD_LDS16((const char*)lut + t * 16 + it * 4096, (char*)sC + t * 16 + it * 4096);

  {
    const int cv = (t & 7) * 8;
    #pragma unroll
    for (int rep = 0; rep < 4; ++rep) {
      int w = (t >> 3) + 32 * rep;
      bf16x8 v = *(const bf16x8*)(xn + ((size_t)bh * W_ + w) * D_ + c0 + cv);
      #pragma unroll
      for (int i = 0; i < 8; ++i) sXt[(cv + i) * KP + w] = ((const bf16*)&v)[i];
    }
  }
  __syncthreads();
  const bf16* sC1 = sC;
  const bf16* sC2 = sC + 10880;

  const int wave = t >> 6, lane = t & 63, l16 = lane & 15, quad = lane >> 4;
  const int ni = (wave == 0) ? 2 : 1;
  int itile[2] = {wave, 4};
  f32x4 accR[2][4], accI[2][4];
  #pragma unroll
  for (int ii = 0; ii < 2; ++ii)
    #pragma unroll
    for (int j = 0; j < 4; ++j) { accR[ii][j] = (f32x4){0,0,0,0}; accI[ii][j] = (f32x4){0,0,0,0}; }

  for (int s = 0; s < 4; ++s) {
    const int kof = s * 32 + quad * 8;
    bf16x8 bfrag[4];
    #pragma unroll
    for (int j = 0; j < 4; ++j) bfrag[j] = FRAG(sXt, KP, j * 16 + l16, kof);
    for (int ii = 0; ii < ni; ++ii) {
      const int arow = 16 * itile[ii] + l16;
      bf16x8 a1 = FRAG(sC1, KP, arow, kof);
      bf16x8 a2 = FRAG(sC2, KP, arow, kof);
      #pragma unroll
      for (int j = 0; j < 4; ++j) {
        accR[ii][j] = __builtin_amdgcn_mfma_f32_16x16x32_bf16(a1, bfrag[j], accR[ii][j], 0, 0, 0);
        accI[ii][j] = __builtin_amdgcn_mfma_f32_16x16x32_bf16(a2, bfrag[j], accI[ii][j], 0, 0, 0);
      }
    }
  }
  for (int ii = 0; ii < ni; ++ii) {
    #pragma unroll
    for (int r = 0; r < 4; ++r) {
      const int f = 16 * itile[ii] + quad * 4 + r;
      if (f >= WF_) continue;
      const size_t ob = ((size_t)bh * WF_ + f) * D_ + c0;
      #pragma unroll
      for (int j = 0; j < 4; ++j) {
        fr[ob + j * 16 + l16] = __float2bfloat16(accR[ii][j][r]);
        fi[ob + j * 16 + l16] = __float2bfloat16(accI[ii][j][r]);
      }
    }
  }
}

// ============ S2: FFT along H as MFMA GEMM. block=(b*WF+f, ctile64) ============
__global__ __launch_bounds__(256) void s2_ffth(
    const bf16* __restrict__ inr, const bf16* __restrict__ ini,
    bf16* __restrict__ outr, bf16* __restrict__ outi, const bf16* __restrict__ lut) {
  const int KP = 72;  // 64 + pad (144 B rows)
  __shared__ __align__(16) bf16 sT[14336];       // Tr @0, Ti @4608, Tn @9216 (+pad)
  __shared__ __align__(16) bf16 sFtr[64 * 72];
  __shared__ __align__(16) bf16 sFti[64 * 72];
  const int t = threadIdx.x;
  const int b = blockIdx.x / WF_;
  const int f = blockIdx.x % WF_;
  const int c0 = blockIdx.y * 64;

  #pragma unroll
  for (int it = 0; it < 7; ++it)
    GLOAD_LDS16((const char*)lut + t * 16 + it * 4096, (char*)sT + t * 16 + it * 4096);

  {
    const int cv = (t & 7) * 8;
    #pragma unroll
    for (int rep = 0; rep < 2; ++rep) {
      int h = (t >> 3) + 32 * rep;
      size_t g = ((size_t)(b * H_ + h) * WF_ + f) * D_ + c0 + cv;
      bf16x8 vr = *(const bf16x8*)(inr + g);
      bf16x8 vi = *(const bf16x8*)(ini + g);
      #pragma unroll
      for (int i = 0; i < 8; ++i) {
        sFtr[(cv + i) * KP + h] = ((const bf16*)&vr)[i];
        sFti[(cv + i) * KP + h] = ((const bf16*)&vi)[i];
      }
    }
  }
  __syncthreads();
  const bf16* sTr = sT;
  const bf16* sTi = sT + 4608;
  const bf16* sTn = sT + 9216;

  const int wave = t >> 6, lane = t & 63, l16 = lane & 15, quad = lane >> 4;
  f32x4 accR[4], accI[4];
  #pragma unroll
  for (int j = 0; j < 4; ++j) { accR[j] = (f32x4){0,0,0,0}; accI[j] = (f32x4){0,0,0,0}; }

  #pragma unroll
  for (int s = 0; s < 2; ++s) {
    const int kof = s * 32 + quad * 8;
    const int arow = 16 * wave + l16;
    bf16x8 ar = FRAG(sTr, KP, arow, kof);
    bf16x8 ai = FRAG(sTi, KP, arow, kof);
    bf16x8 an = FRAG(sTn, KP, arow, kof);
    #pragma unroll
    for (int j = 0; j < 4; ++j) {
      const int brow = j * 16 + l16;
      bf16x8 br = FRAG(sFtr, KP, brow, kof);
      bf16x8 bi = FRAG(sFti, KP, brow, kof);
      accR[j] = __builtin_amdgcn_mfma_f32_16x16x32_bf16(ar, br, accR[j], 0, 0, 0);
      accR[j] = __builtin_amdgcn_mfma_f32_16x16x32_bf16(an, bi, accR[j], 0, 0, 0);
      accI[j] = __builtin_amdgcn_mfma_f32_16x16x32_bf16(ai, br, accI[j], 0, 0, 0);
      accI[j] = __builtin_amdgcn_mfma_f32_16x16x32_bf16(ar, bi, accI[j], 0, 0, 0);
    }
  }
  #pragma unroll
  for (int r = 0; r < 4; ++r) {
    const int k = 16 * wave + quad * 4 + r;
    const size_t ob = ((size_t)(b * H_ + k) * WF_ + f) * D_ + c0;
    #pragma unroll
    for (int j = 0; j < 4; ++j) {
      outr[ob + j * 16 + l16] = __float2bfloat16(accR[j][r]);
      outi[ob + j * 16 + l16] = __float2bfloat16(accI[j][r]);
    }
  }
}

// ============ S3: irfft along W + residual, MFMA. block=(bh, ctile64) ============
__global__ __launch_bounds__(256) void s3_irfftw(
    const bf16* __restrict__ fr, const bf16* __restrict__ fi,
    const bf16* __restrict__ lut, const float* __restrict__ x0, bf16* __restrict__ xsp) {
  const int KP = 104;  // 96 + pad (208 B rows)
  __shared__ __align__(16) bf16 sC[26624];       // Cr @0, Ci @13312
  __shared__ __align__(16) bf16 sGtr[64 * 104];
  __shared__ __align__(16) bf16 sGti[64 * 104];
  const int t = threadIdx.x;
  const int bh = blockIdx.x;
  const int c0 = blockIdx.y * 64;

  #pragma unroll
  for (int it = 0; it < 13; ++it)
    GLOAD_LDS16((const char*)lut + t * 16 + it * 4096, (char*)sC + t * 16 + it * 4096);

  {
    const int cv = (t & 7) * 8;
    #pragma unroll
    for (int rep = 0; rep < 2; ++rep) {
      int f = (t >> 3) + 32 * rep;
      size_t g = ((size_t)bh * WF_ + f) * D_ + c0 + cv;
      bf16x8 vr = *(const bf16x8*)(fr + g);
      bf16x8 vi = *(const bf16x8*)(fi + g);
      #pragma unroll
      for (int i = 0; i < 8; ++i) {
        sGtr[(cv + i) * KP + f] = ((const bf16*)&vr)[i];
        sGti[(cv + i) * KP + f] = ((const bf16*)&vi)[i];
      }
    }
    if (t < 8) {  // f = 64 row
      size_t g = ((size_t)bh * WF_ + 64) * D_ + c0 + cv;
      bf16x8 vr = *(const bf16x8*)(fr + g);
      bf16x8 vi = *(const bf16x8*)(fi + g);
      #pragma unroll
      for (int i = 0; i < 8; ++i) {
        sGtr[(cv + i) * KP + 64] = ((const bf16*)&vr)[i];
        sGti[(cv + i) * KP + 64] = ((const bf16*)&vi)[i];
      }
    }
    const bf16 z = __float2bfloat16(0.f);
    for (int e = t; e < 64 * 31; e += 256) {
      int c = e / 31, f = 65 + (e - (e / 31) * 31);
      sGtr[c * KP + f] = z;
      sGti[c * KP + f] = z;
    }
  }
  __syncthreads();
  const bf16* sCr = sC;
  const bf16* sCi = sC + 13312;

  const int wave = t >> 6, lane = t & 63, l16 = lane & 15, quad = lane >> 4;
  f32x4 acc[2][4];
  #pragma unroll
  for (int ii = 0; ii < 2; ++ii)
    #pragma unroll
    for (int j = 0; j < 4; ++j) acc[ii][j] = (f32x4){0,0,0,0};

  #pragma unroll
  for (int s = 0; s < 3; ++s) {
    const int kof = s * 32 + quad * 8;
    bf16x8 br[4], bi[4];
    #pragma unroll
    for (int j = 0; j < 4; ++j) {
      br[j] = FRAG(sGtr, KP, j * 16 + l16, kof);
      bi[j] = FRAG(sGti, KP, j * 16 + l16, kof);
    }
    #pragma unroll
    for (int ii = 0; ii < 2; ++ii) {
      const int arow = 16 * (wave + 4 * ii) + l16;
      bf16x8 a1 = FRAG(sCr, KP, arow, kof);
      bf16x8 a2 = FRAG(sCi, KP, arow, kof);
      #pragma unroll
      for (int j = 0; j < 4; ++j) {
        acc[ii][j] = __builtin_amdgcn_mfma_f32_16x16x32_bf16(a1, br[j], acc[ii][j], 0, 0, 0);
        acc[ii][j] = __builtin_amdgcn_mfma_f32_16x16x32_bf16(a2, bi[j], acc[ii][j], 0, 0, 0);
      }
    }
  }
  #pragma unroll
  for (int ii = 0; ii < 2; ++ii) {
    #pragma unroll
    for (int r = 0; r < 4; ++r) {
      const int w = 16 * (wave + 4 * ii) + quad * 4 + r;
      const size_t ob = ((size_t)bh * W_ + w) * D_ + c0;
      #pragma unroll
      for (int j = 0; j < 4; ++j) {
        const size_t o = ob + j * 16 + l16;
        xsp[o] = __float2bfloat16(acc[ii][j][r] + x0[o]);
      }
    }
  }
}

// ============ block-diagonal complex MLP as MFMA, in place ============
__global__ __launch_bounds__(256) void blockmlp_mfma(
    bf16* __restrict__ gr, bf16* __restrict__ gi,
    const float* __restrict__ w1, const float* __restrict__ b1,
    const float* __restrict__ w2, const float* __restrict__ b2) {
  const int KP = 104;  // 96 + pad (208 B rows: 13x16B slots -> conflict-free b128)
  __shared__ __align__(16) bf16 sA[128 * 104];
  __shared__ __align__(16) bf16 sW[96 * 104];
  const int t = threadIdx.x;
  const int p0 = blockIdx.x * 64;
  const int nb = blockIdx.y;
  const int cbase = nb * BS_;

  #pragma unroll
  for (int it = 0; it < 3; ++it) {
    int task = t + 256 * it;          // 0..767
    int r = task / 12, jv = task - r * 12;
    size_t g = (size_t)(p0 + r) * D_ + cbase + jv * 8;
    bf16x8 vr = *(const bf16x8*)(gr + g);
    bf16x8 vi = *(const bf16x8*)(gi + g);
    bf16x8 u8, v8;
    #pragma unroll
    for (int i = 0; i < 8; ++i) {
      float xr = __bfloat162float(((const bf16*)&vr)[i]);
      float xi = __bfloat162float(((const bf16*)&vi)[i]);
      ((bf16*)&u8)[i] = __float2bfloat16(xr - xi);
      ((bf16*)&v8)[i] = __float2bfloat16(xr + xi);
    }
    *(bf16x8*)(sA + r * KP + jv * 8) = u8;
    *(bf16x8*)(sA + (64 + r) * KP + jv * 8) = v8;
  }
  {
    const float* wsrc = w1 + nb * BS_ * BS_;
    #pragma unroll
    for (int it = 0; it < 9; ++it) {
      int e4 = t + 256 * it;          // 0..2303 tasks of 4 elems
      int j = e4 / 24, m4 = (e4 - j * 24) * 4;
      float4 ld = *(const float4*)(wsrc + j * 96 + m4);
      sW[(m4 + 0) * KP + j] = __float2bfloat16(ld.x);
      sW[(m4 + 1) * KP + j] = __float2bfloat16(ld.y);
      sW[(m4 + 2) * KP + j] = __float2bfloat16(ld.z);
      sW[(m4 + 3) * KP + j] = __float2bfloat16(ld.w);
    }
  }
  __syncthreads();

  const int wave = t >> 6, lane = t & 63, l16 = lane & 15, quad = lane >> 4;
  f32x4 accU[6], accV[6];
  #pragma unroll
  for (int n = 0; n < 6; ++n) { accU[n] = (f32x4){0,0,0,0}; accV[n] = (f32x4){0,0,0,0}; }

  #pragma unroll
  for (int s = 0; s < 3; ++s) {
    const int kof = s * 32 + quad * 8;
    bf16x8 au = FRAG(sA, KP, wave * 16 + l16, kof);
    bf16x8 av = FRAG(sA, KP, 64 + wave * 16 + l16, kof);
    bf16x8 bw[6];
    #pragma unroll
    for (int n = 0; n < 6; ++n) bw[n] = FRAG(sW, KP, n * 16 + l16, kof);
    #pragma unroll
    for (int n = 0; n < 6; ++n) {
      accU[n] = __builtin_amdgcn_mfma_f32_16x16x32_bf16(au, bw[n], accU[n], 0, 0, 0);
      accV[n] = __builtin_amdgcn_mfma_f32_16x16x32_bf16(av, bw[n], accV[n], 0, 0, 0);
    }
  }
  __syncthreads();  // all layer-1 reads of sA/sW complete

  {
    const float* wsrc = w2 + nb * BS_ * BS_;
    #pragma unroll
    for (int it = 0; it < 9; ++it) {
      int e4 = t + 256 * it;
      int j = e4 / 24, m4 = (e4 - j * 24) * 4;
      float4 ld = *(const float4*)(wsrc + j * 96 + m4);
      sW[(m4 + 0) * KP + j] = __float2bfloat16(ld.x);
      sW[(m4 + 1) * KP + j] = __float2bfloat16(ld.y);
      sW[(m4 + 2) * KP + j] = __float2bfloat16(ld.z);
      sW[(m4 + 3) * KP + j] = __float2bfloat16(ld.w);
    }
  }
  #pragma unroll
  for (int n = 0; n < 6; ++n) {
    const float bias = b1[cbase + n * 16 + l16];
    #pragma unroll
    for (int r = 0; r < 4; ++r) {
      float o1r = fmaxf(accU[n][r] + bias, 0.0f);
      float o1i = fmaxf(accV[n][r] + bias, 0.0f);
      const int row = wave * 16 + quad * 4 + r;
      sA[row * KP + n * 16 + l16]        = __float2bfloat16(o1r - o1i);  // p
      sA[(64 + row) * KP + n * 16 + l16] = __float2bfloat16(o1r + o1i);  // q
    }
  }
  __syncthreads();

  #pragma unroll
  for (int n = 0; n < 6; ++n) { accU[n] = (f32x4){0,0,0,0}; accV[n] = (f32x4){0,0,0,0}; }
  #pragma unroll
  for (int s = 0; s < 3; ++s) {
    const int kof = s * 32 + quad * 8;
    bf16x8 ap = FRAG(sA, KP, wave * 16 + l16, kof);
    bf16x8 aq = FRAG(sA, KP, 64 + wave * 16 + l16, kof);
    bf16x8 bw[6];
    #pragma unroll
    for (int n = 0; n < 6; ++n) bw[n] = FRAG(sW, KP, n * 16 + l16, kof);
    #pragma unroll
    for (int n = 0; n < 6; ++n) {
      accU[n] = __builtin_amdgcn_mfma_f32_16x16x32_bf16(ap, bw[n], accU[n], 0, 0, 0);
      accV[n] = __builtin_amdgcn_mfma_f32_16x16x32_bf16(aq, bw[n], accV[n], 0, 0, 0);
    }
  }

  #pragma unroll
  for (int n = 0; n < 6; ++n) {
    const float bias = b2[cbase + n * 16 + l16];
    #pragma unroll
    for (int r = 0; r < 4; ++r) {
      const int row = wave * 16 + quad * 4 + r;
      float o2r = accU[n][r] + bias;
      float o2i = accV[n][r] + bias;
      o2r = (o2r > LAM_) ? (o2r - LAM_) : ((o2r < -LAM_) ? (o2r + LAM_) : 0.0f);
      o2i = (o2i > LAM_) ? (o2i - LAM_) : ((o2i < -LAM_) ? (o2i + LAM_) : 0.0f);
      const size_t o = (size_t)(p0 + row) * D_ + cbase + n * 16 + l16;
      gr[o] = __float2bfloat16(o2r);
      gi[o] = __float2bfloat16(o2i);
    }
  }
}

// ---------------- weight transpose+cast: W (K x N fp32) -> Wt (N x K bf16) ----
__global__ __launch_bounds__(256) void wtrans_kernel(
    const float* __restrict__ Wm, bf16* __restrict__ Wt, int K, int N) {
  __shared__ float tile[32][33];
  const int n0 = blockIdx.x * 32;
  const int k0 = blockIdx.y * 32;
  const int tx = threadIdx.x & 31;
  const int ty = threadIdx.x >> 5;   // 0..7
  #pragma unroll
  for (int r = 0; r < 32; r += 8)
    tile[ty + r][tx] = Wm[(size_t)(k0 + ty + r) * N + n0 + tx];
  __syncthreads();
  #pragma unroll
  for (int r = 0; r < 32; r += 8)
    Wt[(size_t)(n0 + ty + r) * K + k0 + tx] = __float2bfloat16(tile[tx][ty + r]);
}

// ---------------- MFMA GEMM: out = act(A @ Bt^T + bias) [+ resid] ----------------
// BM=128, BN=256, BK=64, 512 threads (8 waves 2Mx4N), TRIPLE-buffered LDS with
// counted vmcnt(6): stage kt+2 targets buf (kt+2)%3 whose last read ended at
// iteration kt-1's barrier (issue-after-read, provably race-free). End-of-iter
// vmcnt(6) retires exactly kt+1's 6 loads (issued a full iteration earlier).
// ds_read swizzle: 128B rows are a 32-way conflict; slot ^= (row&7) involution
// applied on BOTH global source column and read slot (rule 21).
template <int MODE, typename TOUT>
__global__ __launch_bounds__(512) void mfma_gemm_kernel(
    const bf16* __restrict__ A, const bf16* __restrict__ Bt,
    const float* __restrict__ bias, const bf16* __restrict__ resid,
    TOUT* __restrict__ out, int M, int N, int K) {
  // per buffer (24576 elems): A[128][64] @0, B[256][64] @8192
  __shared__ __align__(16) bf16 sM[3 * 24576];   // 144 KiB
  const int t = threadIdx.x;
  const int m0 = blockIdx.x * 128;
  const int n0 = blockIdx.y * 256;
  const int wave = t >> 6, lane = t & 63, l16 = lane & 15, quad = lane >> 4;
  const int wr = wave >> 2, wc = wave & 3;   // 2M x 4N

  // staging: thread t -> rows t>>3 (+64*l), linear LDS slot t&7; source col swizzled
  const int srow = t >> 3;
  const int scol = ((t & 7) ^ (srow & 7)) * 8;
  const bf16* Ag0 = A + (size_t)(m0 + srow) * K + scol;
  const bf16* Ag1 = A + (size_t)(m0 + 64 + srow) * K + scol;
  const bf16* Bg0 = Bt + (size_t)(n0 + srow) * K + scol;
  const bf16* Bg1 = Bt + (size_t)(n0 + 64 + srow) * K + scol;
  const bf16* Bg2 = Bt + (size_t)(n0 + 128 + srow) * K + scol;
  const bf16* Bg3 = Bt + (size_t)(n0 + 192 + srow) * K + scol;

  // read offsets: row*64 + ((4s+quad)^(row&7))*8 ; row&7 == l16&7 for all frags
  int arow[4], brow[4], sofs[2];
  #pragma unroll
  for (int i = 0; i < 4; ++i) arow[i] = (wr * 64 + i * 16 + l16) * 64;
  #pragma unroll
  for (int j = 0; j < 4; ++j) brow[j] = 8192 + (wc * 64 + j * 16 + l16) * 64;
  sofs[0] = (quad ^ (l16 & 7)) * 8;
  sofs[1] = ((4 + quad) ^ (l16 & 7)) * 8;

  f32x4 acc[4][4];
  #pragma unroll
  for (int i = 0; i < 4; ++i)
    #pragma unroll
    for (int j = 0; j < 4; ++j) acc[i][j] = (f32x4){0.f, 0.f, 0.f, 0.f};

#define STAGE6(bb, ko) do { \
    bf16* d_ = sM + (bb) * 24576; \
    GLOAD_LDS16(Ag0 + (ko), d_ + t * 8); \
    GLOAD_LDS16(Ag1 + (ko), d_ + 4096 + t * 8); \
    GLOAD_LDS16(Bg0 + (ko), d_ + 8192 + t * 8); \
    GLOAD_LDS16(Bg1 + (ko), d_ + 12288 + t * 8); \
    GLOAD_LDS16(Bg2 + (ko), d_ + 16384 + t * 8); \
    GLOAD_LDS16(Bg3 + (ko), d_ + 20480 + t * 8); } while (0)

#define PHASE(bb, s) do { \
    const bf16* base_ = sM + (bb) * 24576; \
    bf16x8 af[4], bfr[4]; \
    _Pragma("unroll") \
    for (int i = 0; i < 4; ++i) af[i] = *(const bf16x8*)(base_ + arow[i] + sofs[s]); \
    _Pragma("unroll") \
    for (int j = 0; j < 4; ++j) bfr[j] = *(const bf16x8*)(base_ + brow[j] + sofs[s]); \
    __builtin_amdgcn_s_setprio(1); \
    _Pragma("unroll") \
    for (int i = 0; i < 4; ++i) \
      _Pragma("unroll") \
      for (int j = 0; j < 4; ++j) \
        acc[i][j] = __builtin_amdgcn_mfma_f32_16x16x32_bf16(af[i], bfr[j], acc[i][j], 0, 0, 0); \
    __builtin_amdgcn_s_setprio(0); \
  } while (0)

  const int NT = K >> 6;   // 12 (MODE 0) / 48 (MODE 1)
  STAGE6(0, 0);
  STAGE6(1, 64);
  asm volatile("s_waitcnt vmcnt(6)" ::: "memory");   // kt0 landed; kt1 in flight
  __builtin_amdgcn_s_barrier();
  asm volatile("" ::: "memory");

  int cur = 0;
  for (int kt = 0; kt < NT; ++kt) {
    int stg = cur + 2; if (stg >= 3) stg -= 3;
    const bool more = (kt + 2 < NT);
    if (more) STAGE6(stg, (size_t)(kt + 2) << 6);   // safe: buf last read at kt-1
    PHASE(cur, 0);
    PHASE(cur, 1);
    if (more) { asm volatile("s_waitcnt vmcnt(6)" ::: "memory"); }  // retire kt+1's 6
    else      { asm volatile("s_waitcnt vmcnt(0)" ::: "memory"); }
    __builtin_amdgcn_s_barrier();
    asm volatile("" ::: "memory");
    ++cur; if (cur == 3) cur = 0;
  }
#undef STAGE6
#undef PHASE

  #pragma unroll
  for (int i = 0; i < 4; ++i) {
    #pragma unroll
    for (int j = 0; j < 4; ++j) {
      const int n = n0 + wc * 64 + j * 16 + l16;
      const float bz = bias[n];
      #pragma unroll
      for (int r = 0; r < 4; ++r) {
        const int m = m0 + wr * 64 + i * 16 + quad * 4 + r;
        float v = acc[i][j][r] + bz;
        if (MODE == 0) {
          // gelu(x) ~= x * sigmoid(1.5957691*(x + 0.044715 x^3)); |err| < 4e-4
          float q = v * fmaf(0.044715f, v * v, 1.0f);
          float e = __expf(-1.5957691216f * q);
          v = v * __builtin_amdgcn_rcpf(1.0f + e);
        } else {
          v += ldf(resid + (size_t)m * N + n);
        }
        stf(out + (size_t)m * N + n, v);
      }
    }
  }
}

extern "C" void kernel_launch(void* const* d_in, const int* in_sizes, int n_in,
                              void* d_out, int out_size, void* d_ws, size_t ws_size,
                              hipStream_t stream) {
  const float* x     = (const float*)d_in[0];
  const float* w1    = (const float*)d_in[1];
  const float* b1    = (const float*)d_in[2];
  const float* w2    = (const float*)d_in[3];
  const float* b2    = (const float*)d_in[4];
  const float* ln1w  = (const float*)d_in[5];
  const float* ln1b  = (const float*)d_in[6];
  const float* ln2w  = (const float*)d_in[7];
  const float* ln2b  = (const float*)d_in[8];
  const float* mlpw1 = (const float*)d_in[9];
  const float* mlpb1 = (const float*)d_in[10];
  const float* mlpw2 = (const float*)d_in[11];
  const float* mlpb2 = (const float*)d_in[12];
  float* out = (float*)d_out;

  const size_t SPA = (size_t)B_ * H_ * W_ * D_;   // 25,165,824 elems
  const size_t FRE = (size_t)B_ * H_ * WF_ * D_;  // 12,779,520 elems
  bf16* ws   = (bf16*)d_ws;
  bf16* bufA = ws;               // xn, later xsp (residual2)
  bf16* Fr   = bufA + SPA;
  bf16* Fi   = Fr + FRE;
  bf16* Gr   = Fi + FRE;
  bf16* Gi   = Gr + FRE;
  bf16* hid  = Fr;                              // GEMM-phase overlays
  bf16* xn2c = Gr;
  bf16* w1t  = xn2c + (size_t)CHTOK_ * D_;
  bf16* w2t  = w1t + (size_t)D_ * HID_;

  // twiddle LUTs live in d_out (dead until the final GEMM phase writes it)
  bf16* lut = (bf16*)d_out;

  const int nspec = B_ * H_ * WF_;  // 16640

  hipLaunchKernelGGL(lut_init, dim3(LUT_TOTAL / 256), dim3(256), 0, stream, lut);
  hipLaunchKernelGGL((ln_kernel<float>), dim3(NTOK_), dim3(256), 0, stream, x, ln1w, ln1b, bufA);
  hipLaunchKernelGGL(s1_rfftw, dim3(B_ * H_, D_ / 64), dim3(256), 0, stream,
                     bufA, lut + LUT_S1_OFF, Fr, Fi);
  hipLaunchKernelGGL(s2_ffth, dim3(B_ * WF_, D_ / 64), dim3(256), 0, stream,
                     Fr, Fi, Gr, Gi, lut + LUT_S2M_OFF);
  hipLaunchKernelGGL(blockmlp_mfma, dim3(nspec / 64, NB_), dim3(256), 0, stream,
                     Gr, Gi, w1, b1, w2, b2);
  hipLaunchKernelGGL(s2_ffth, dim3(B_ * WF_, D_ / 64), dim3(256), 0, stream,
                     Gr, Gi, Fr, Fi, lut + LUT_S2P_OFF);
  hipLaunchKernelGGL(s3_irfftw, dim3(B_ * H_, D_ / 64), dim3(256), 0, stream,
                     Fr, Fi, lut + LUT_S3_OFF, x, bufA);

  hipLaunchKernelGGL(wtrans_kernel, dim3(HID_ / 32, D_ / 32), dim3(256), 0, stream,
                     mlpw1, w1t, D_, HID_);
  hipLaunchKernelGGL(wtrans_kernel, dim3(D_ / 32, HID_ / 32), dim3(256), 0, stream,
                     mlpw2, w2t, HID_, D_);

  for (int c = 0; c < B_; ++c) {
    const bf16* rs = bufA + (size_t)c * CHTOK_ * D_;
    float* oc = out + (size_t)c * CHTOK_ * D_;
    hipLaunchKernelGGL((ln_kernel<bf16>), dim3(CHTOK_), dim3(256), 0, stream,
                       rs, ln2w, ln2b, xn2c);
    hipLaunchKernelGGL((mfma_gemm_kernel<0, bf16>), dim3(CHTOK_ / 128, HID_ / 256), dim3(512), 0,
                       stream, xn2c, w1t, mlpb1, (const bf16*)nullptr, hid, CHTOK_, HID_, D_);
    hipLaunchKernelGGL((mfma_gemm_kernel<1, float>), dim3(CHTOK_ / 128, D_ / 256), dim3(512), 0,
                       stream, hid, w2t, mlpb2, rs, oc, CHTOK_, D_, HID_);
  }
}